// Round 2
// baseline (2088.893 us; speedup 1.0000x reference)
//
#include <hip/hip_runtime.h>
#include <math.h>

// DNC: B=32,T=64,I=64,O=64,H=512,N=128,W=64,IF=198
// R15: P2 replicated into every P1 wg (8x redundant, it's cheap) -> rvec is
// LDS-local, killing the rvec global hop + wave-7 latency tail. One global
// hop per step remains (itf partial all-gather), partially hidden under the
// out-projection. 128 wgs, jb = wg%8 colocates weight-slice sharers per XCD.
#define Bb 32
#define Tt 64
#define Ii 64
#define Oo 64
#define Hh 512
#define Nn 128
#define Wd 64
#define IFs 198
#define KV 640
#define G4 2048

#define NWG 128
#define NT 512

// ---- LDS layout (float offsets)
#define L_V      0        /* 640 rows x 2 batches interleaved = 1280 */
#define L_BS     1280     /* 256 (bias slice, 64 float4) */
#define L_CC     1536     /* 128 cell state */
#define L_HSL    1664     /* 128 h slice */
#define L_BIF    1792     /* 224 b_if */
#define L_ITF    2016     /* 2 x 224 */
#define L_ERASE  2464     /* 2 x 64 */
#define L_WVEC   2592     /* 2 x 64 */
#define L_USAGE  2720     /* 2 x 128 */
#define L_PREC   2976     /* 2 x 128 */
#define L_RW     3232     /* 2 x 128 */
#define L_WW     3488     /* 2 x 128 */
#define L_SCAN   3744     /* 2 x 128 */
#define L_SS     4000     /* 2 x 128 */
#define L_ALLOC  4256     /* 2 x 128 */
#define L_SCAL   4512     /* 2 x 16 */
#define L_SCR    4544     /* 2 x 1024 */
#define L_PACC   6592     /* 32 rows x 65 float4 = 8320 floats */
#define L_MEM    14912    /* 2 x 128 x 65 = 16640 */
#define SMEM_FLOATS 31552 /* 126208 B */
#define SMEM_BYTES (SMEM_FLOATS * 4)

// WT row permutation: rows = [h(512) | x(64) | rvec(64)].
__device__ __align__(16) float g_WT[KV * G4];
__device__ __align__(16) float g_bsum[G4];
typedef unsigned long long u64;
// Tagged handoffs: u64 = (step_tag << 32) | float_bits. Relaxed agent atomics.
__device__ u64 g_h64[2 * Bb * Hh];   // h, step-parity double buffer, tag t+1
__device__ u64 g_if64[Bb * 8 * 200]; // itf partials [b][jb(8)][o pad200] tag t+1

__device__ __forceinline__ float sigf(float v) { return 1.f / (1.f + expf(-v)); }

__device__ __forceinline__ u64 ldrelax(const u64* p) {
  return __hip_atomic_load(p, __ATOMIC_RELAXED, __HIP_MEMORY_SCOPE_AGENT);
}
__device__ __forceinline__ void tstore(u64* p, unsigned tag, float v) {
  u64 val = ((u64)tag << 32) | (u64)__float_as_uint(v);
  __hip_atomic_store(p, val, __ATOMIC_RELAXED, __HIP_MEMORY_SCOPE_AGENT);
}
__device__ __forceinline__ float fixwait(const u64* p, u64 v, unsigned tag) {
  while ((unsigned)(v >> 32) != tag) {
    __builtin_amdgcn_s_sleep(1);
    v = ldrelax(p);
  }
  return __uint_as_float((unsigned)(v & 0xffffffffu));
}

#define TIN 512
__global__ __launch_bounds__(TIN) void dnc_init(const float* __restrict__ W_ih,
                                                const float* __restrict__ W_hh,
                                                const float* __restrict__ b_ih,
                                                const float* __restrict__ b_hh) {
  __shared__ float tile[64][65];
  const int tid = threadIdx.x;
  int i0 = blockIdx.x * blockDim.x + tid;
  int st = gridDim.x * blockDim.x;
  for (int idx = i0; idx < G4; idx += st) g_bsum[idx] = b_ih[idx] + b_hh[idx];
  for (int idx = i0; idx < 2 * Bb * Hh; idx += st) g_h64[idx] = 0ull;
  for (int idx = i0; idx < Bb * 8 * 200; idx += st) g_if64[idx] = 0ull;

  for (int tileId = blockIdx.x; tileId < 320; tileId += gridDim.x) {
    int tc = tileId >> 5, tj = tileId & 31;
    for (int k = tid; k < 64 * 64; k += TIN) {
      int r = k >> 6, cl = k & 63;
      int j = tj * 64 + r, c = tc * 64 + cl;
      tile[r][cl] = (c < 128) ? W_ih[j * 128 + c] : W_hh[j * 512 + (c - 128)];
    }
    __syncthreads();
    for (int k = tid; k < 64 * 64; k += TIN) {
      int cl = k >> 6, rjj = k & 63;
      int c = tc * 64 + cl;
      // rows: h u -> u ; x c -> 512+c ; rvec -> 576+(c-64)  (== 512+c)
      int rp = (c < 128) ? (512 + c) : (c - 128);
      g_WT[(size_t)rp * G4 + tj * 64 + rjj] = tile[rjj][cl];
    }
    __syncthreads();
  }
}

__global__ __launch_bounds__(NT, 2) void dnc_main(const float* __restrict__ x,
                                                  const float* __restrict__ W_if,
                                                  const float* __restrict__ b_if,
                                                  const float* __restrict__ W_out,
                                                  const float* __restrict__ b_out,
                                                  float* __restrict__ out) {
  extern __shared__ float sm[];
  const int tid = threadIdx.x;
  const int wg = blockIdx.x;
  const int jb = wg & 7;
  const int bb = wg >> 3;
  const int b0 = bb * 2;

  // link state: thread (bl=tid>>8, m=tid&127, kh=(tid>>7)&1) holds
  // L[k?,m]/LT[m,k?] for k in [kh*64, kh*64+64), for batch b0+bl.
  float regL[64], regLT[64];
#pragma unroll
  for (int k = 0; k < 64; ++k) { regL[k] = 0.f; regLT[k] = 0.f; }

  // ---- static init
  if (tid < 64) {
    int gq = tid >> 4, m = tid & 15;
    ((float4*)(sm + L_BS))[tid] = ((const float4*)g_bsum)[gq * 128 + jb * 16 + m];
  }
  if (tid < 128) {
    sm[L_CC + tid] = 0.f;
    sm[L_V + (576 + (tid & 63)) * 2 + (tid >> 6)] = 0.f;  // rvec(-1) = 0
  }
  if (tid < IFs) sm[L_BIF + tid] = b_if[tid];
  if (tid < 256) {
    int bl = tid >> 7, n = tid & 127;
    sm[L_USAGE + bl * 128 + n] = 0.f;
    sm[L_PREC + bl * 128 + n] = 0.f;
    sm[L_RW + bl * 128 + n] = 0.f;
  }
  for (int i = tid; i < 2 * Nn * 65; i += NT) sm[L_MEM + i] = 0.f;
  __syncthreads();
  // prologue: alloc for t=0 from usage=0 (both batches)
  if (tid < 128) {
    const int bl = tid >> 6, li = tid & 63, i0 = 2 * li, i1 = i0 + 1;
    float* USb = sm + L_USAGE + bl * 128;
    float* SSb = sm + L_SS + bl * 128;
    float* SCb = sm + L_SCAN + bl * 128;
    float* ALb = sm + L_ALLOC + bl * 128;
    float u0 = USb[i0], u1 = USb[i1];
    int r0 = 0, r1 = 0;
    for (int jc = 0; jc < 32; ++jc) {
      float4 uj4 = *(const float4*)(USb + jc * 4);
#pragma unroll
      for (int e = 0; e < 4; ++e) {
        float uj = (&uj4.x)[e];
        int j = jc * 4 + e;
        r0 += (uj < u0 || (uj == u0 && j < i0)) ? 1 : 0;
        r1 += (uj < u1 || (uj == u1 && j < i1)) ? 1 : 0;
      }
    }
    SSb[r0] = u0;
    SSb[r1] = u1;
    float s0 = SSb[i0], s1 = SSb[i1];
    float p = s0 * s1;
#pragma unroll
    for (int off = 1; off < 64; off <<= 1) {
      float v = __shfl_up(p, off, 64);
      if (li >= off) p *= v;
    }
    float E = __shfl_up(p, 1, 64);
    if (li == 0) E = 1.f;
    SCb[i0] = E * s0;
    SCb[i1] = E * s0 * s1;
    float ex0 = (r0 > 0) ? SCb[r0 - 1] : 1.f;
    float ex1 = (r1 > 0) ? SCb[r1 - 1] : 1.f;
    ALb[i0] = (1.f - u0) * ex0;
    ALb[i1] = (1.f - u1) * ex1;
  }
  __syncthreads();

  for (int t = 0; t < Tt; ++t) {
    // ---- A: stage h(t-1) + x(t), batch-interleaved [row][bl]
    {
      const u64* hsrc = g_h64 + (size_t)((t + 1) & 1) * (Bb * Hh);
      const int u = tid;
      const u64* a0 = hsrc + (size_t)b0 * Hh + u;
      const u64* a1 = hsrc + (size_t)(b0 + 1) * Hh + u;
      u64 v0 = ldrelax(a0), v1 = ldrelax(a1);
      float2 hh;
      hh.x = fixwait(a0, v0, (unsigned)t);
      hh.y = fixwait(a1, v1, (unsigned)t);
      *(float2*)(sm + L_V + u * 2) = hh;
      if (tid < 128) {
        const int bl2 = tid >> 6, i = tid & 63;
        sm[L_V + (512 + i) * 2 + bl2] = x[((size_t)(b0 + bl2) * Tt + t) * Ii + i];
      }
    }
    __syncthreads();
    // ---- B: GEMV, 640 rows (incl. LOCAL rvec rows 576-639), weights read once
    {
      const int fg = tid & 31, ks = tid >> 5;
      const int fcolA = ((fg >> 4) * 128) + jb * 16 + (fg & 15);
      const float* v2 = sm + L_V + ks * 80;
      const float4* wpA = (const float4*)g_WT + (size_t)(ks * 40) * 512 + fcolA;
      float4 aA0 = {0.f, 0.f, 0.f, 0.f}, aA1 = {0.f, 0.f, 0.f, 0.f};
      float4 aB0 = {0.f, 0.f, 0.f, 0.f}, aB1 = {0.f, 0.f, 0.f, 0.f};
#pragma unroll 4
      for (int r = 0; r < 40; ++r) {
        float4 wA = wpA[(size_t)r * 512];
        float4 wB = wpA[(size_t)r * 512 + 256];
        float2 vv = *(const float2*)(v2 + r * 2);
        aA0.x += wA.x * vv.x; aA0.y += wA.y * vv.x; aA0.z += wA.z * vv.x; aA0.w += wA.w * vv.x;
        aA1.x += wA.x * vv.y; aA1.y += wA.y * vv.y; aA1.z += wA.z * vv.y; aA1.w += wA.w * vv.y;
        aB0.x += wB.x * vv.x; aB0.y += wB.y * vv.x; aB0.z += wB.z * vv.x; aB0.w += wB.w * vv.x;
        aB1.x += wB.x * vv.y; aB1.y += wB.y * vv.y; aB1.z += wB.z * vv.y; aB1.w += wB.w * vv.y;
      }
      float4* pacc = (float4*)(sm + L_PACC);
      pacc[(ks * 2 + 0) * 65 + fg] = aA0;
      pacc[(ks * 2 + 1) * 65 + fg] = aA1;
      pacc[(ks * 2 + 0) * 65 + fg + 32] = aB0;
      pacc[(ks * 2 + 1) * 65 + fg + 32] = aB1;
    }
    __syncthreads();
    // ---- C: K-reduce (16 partials) + LSTM; publish h
    if (tid < 128) {
      const int bl = tid >> 6, l = tid & 63;
      const float* pb = sm + L_PACC + bl * 260 + l;
      float gv0 = 0.f, gv1 = 0.f, gv2 = 0.f, gv3 = 0.f;
#pragma unroll
      for (int ks = 0; ks < 16; ++ks) {
        const float* pk = pb + ks * 520;
        gv0 += pk[0];
        gv1 += pk[64];
        gv2 += pk[128];
        gv3 += pk[192];
      }
      float ig = gv0 + sm[L_BS + l];
      float fg = gv1 + sm[L_BS + 64 + l];
      float gg = gv2 + sm[L_BS + 128 + l];
      float og = gv3 + sm[L_BS + 192 + l];
      float co = sm[L_CC + bl * 64 + l];
      float cn = sigf(fg) * co + sigf(ig) * tanhf(gg);
      float hn = sigf(og) * tanhf(cn);
      sm[L_CC + bl * 64 + l] = cn;
      sm[L_HSL + bl * 64 + l] = hn;
      tstore(g_h64 + (size_t)(t & 1) * (Bb * Hh) + (size_t)(b0 + bl) * Hh + jb * 64 + l,
             (unsigned)(t + 1), hn);
    }
    __syncthreads();
    // ---- C2: itf partial (W_if from L2, jb-colocated) + publish; then
    //          issue all-gather polls; hide the hop under out(t-1); gather.
    if (tid < 2 * IFs) {
      const int o = tid >> 1, bl = tid & 1;
      const float4* wr = (const float4*)(W_if + (size_t)o * Hh + jb * 64);
      const float4* h4 = (const float4*)(sm + L_HSL + bl * 64);
      float acc = 0.f;
#pragma unroll 8
      for (int c4 = 0; c4 < 16; ++c4) {
        float4 w = wr[c4]; float4 h = h4[c4];
        acc += w.x * h.x + w.y * h.y + w.z * h.z + w.w * h.w;
      }
      tstore(g_if64 + ((size_t)(b0 + bl) * 8 + jb) * 200 + o, (unsigned)(t + 1), acc);
    }
    const u64* pp0; const u64* pp1; const u64* pp2; const u64* pp3;
    const u64* pp4; const u64* pp5; const u64* pp6; const u64* pp7;
    u64 pv0 = 0, pv1 = 0, pv2 = 0, pv3 = 0, pv4 = 0, pv5 = 0, pv6 = 0, pv7 = 0;
    if (tid < 2 * IFs) {
      const int o = tid >> 1, bl = tid & 1;
      const u64* base = g_if64 + (size_t)(b0 + bl) * 8 * 200 + o;
      pp0 = base;        pp1 = base + 200;  pp2 = base + 400;  pp3 = base + 600;
      pp4 = base + 800;  pp5 = base + 1000; pp6 = base + 1200; pp7 = base + 1400;
      pv0 = ldrelax(pp0); pv1 = ldrelax(pp1); pv2 = ldrelax(pp2); pv3 = ldrelax(pp3);
      pv4 = ldrelax(pp4); pv5 = ldrelax(pp5); pv6 = ldrelax(pp6); pv7 = ldrelax(pp7);
    }
    if (t > 0 && tid < 256) {  // out(t-1): needs only staged h(t-1) + local rvec(t-1)
      const int g = tid >> 4, seg = tid & 15;
      const int o = jb * 8 + (g >> 1), bl = g & 1;
      const float4* w4 = (const float4*)(W_out + (size_t)o * 576) + seg * 9;
      float p = 0.f;
#pragma unroll
      for (int q = 0; q < 9; ++q) {
        float4 w = w4[q];
        int v = seg * 36 + q * 4;
        int r0 = (v < 512) ? v : v + 64;  // skip x rows; rvec at 576+
        p += w.x * sm[L_V + (r0 + 0) * 2 + bl];
        p += w.y * sm[L_V + (r0 + 1) * 2 + bl];
        p += w.z * sm[L_V + (r0 + 2) * 2 + bl];
        p += w.w * sm[L_V + (r0 + 3) * 2 + bl];
      }
      p += __shfl_down(p, 8, 16);
      p += __shfl_down(p, 4, 16);
      p += __shfl_down(p, 2, 16);
      p += __shfl_down(p, 1, 16);
      if (seg == 0) out[((size_t)(b0 + bl) * Tt + (t - 1)) * Oo + o] = p + b_out[o];
    }
    if (tid < 2 * IFs) {
      const int o = tid >> 1, bl = tid & 1;
      float sA = fixwait(pp0, pv0, (unsigned)(t + 1))
               + fixwait(pp1, pv1, (unsigned)(t + 1))
               + fixwait(pp2, pv2, (unsigned)(t + 1))
               + fixwait(pp3, pv3, (unsigned)(t + 1));
      float sB = fixwait(pp4, pv4, (unsigned)(t + 1))
               + fixwait(pp5, pv5, (unsigned)(t + 1))
               + fixwait(pp6, pv6, (unsigned)(t + 1))
               + fixwait(pp7, pv7, (unsigned)(t + 1));
      sm[L_ITF + bl * 224 + o] = (sA + sB) + sm[L_BIF + o];
    }
    __syncthreads();
    // ---- E2: scalars + ww + usage (64 thr per batch: waves 0,1)
    float kn_r = 0.f, rstr_r = 0.f, rm0_r = 0.f, rm1_r = 0.f, rm2_r = 0.f;
    if (tid < 128) {
      const int bl = tid >> 6, li = tid & 63, i0 = 2 * li, i1 = i0 + 1;
      const float* ITFb = sm + L_ITF + bl * 224;
      float wgag = sigf(ITFb[128]) * sigf(ITFb[129]);
      float rs = ITFb[194];
      rstr_r = (rs > 20.f) ? rs : log1pf(expf(rs));
      float m0 = ITFb[195], m1 = ITFb[196], m2 = ITFb[197];
      float mx = fmaxf(m0, fmaxf(m1, m2));
      float e0 = expf(m0 - mx), e1 = expf(m1 - mx), e2 = expf(m2 - mx);
      float es = e0 + e1 + e2;
      rm0_r = e0 / es; rm1_r = e1 / es; rm2_r = e2 / es;
      float rk = ITFb[li];
      sm[L_ERASE + bl * 64 + li] = sigf(rk);
      sm[L_WVEC + bl * 64 + li] = ITFb[64 + li];
      float sq = rk * rk;
#pragma unroll
      for (int off = 32; off > 0; off >>= 1) sq += __shfl_xor(sq, off, 64);
      kn_r = sqrtf(sq) + 1e-8f;
      float* USb = sm + L_USAGE + bl * 128;
      float* WWb = sm + L_WW + bl * 128;
      const float* ALb = sm + L_ALLOC + bl * 128;
      float u0 = USb[i0], u1 = USb[i1];
      float w0 = wgag * ALb[i0];
      float w1 = wgag * ALb[i1];
      WWb[i0] = w0; WWb[i1] = w1;
      USb[i0] = u0 + (1.f - u0) * w0;
      USb[i1] = u1 + (1.f - u1) * w1;
      float wws = w0 + w1;
#pragma unroll
      for (int off = 32; off > 0; off >>= 1) wws += __shfl_xor(wws, off, 64);
      if (li == 0) sm[L_SCAL + bl * 16] = wws;
    }
    __syncthreads();
    // ---- E3: mem update + dot/mn + register link + bw/fw (256 thr per batch)
    {
      const int bl = tid >> 8, s = tid & 255;
      float* MEMb = sm + L_MEM + bl * 8320;
      float* SCRb = sm + L_SCR + bl * 1024;
      const float* WWb = sm + L_WW + bl * 128;
      {
        const int n = s & 127, ws2 = s >> 7;
        const float* ERb = sm + L_ERASE + bl * 64 + ws2 * 32;
        const float* WVb = sm + L_WVEC + bl * 64 + ws2 * 32;
        const float* KFb = sm + L_ITF + bl * 224 + ws2 * 32;
        float wwn = WWb[n];
        float dotp = 0.f, mnp = 0.f;
        const int mbase = n * 65 + ws2 * 32;
#pragma unroll
        for (int hq = 0; hq < 2; ++hq) {
          float4 er[4], wv[4], kf[4];
#pragma unroll
          for (int r = 0; r < 4; ++r) {
            er[r] = *(const float4*)(ERb + hq * 16 + r * 4);
            wv[r] = *(const float4*)(WVb + hq * 16 + r * 4);
            kf[r] = *(const float4*)(KFb + hq * 16 + r * 4);
          }
#pragma unroll
          for (int q = 0; q < 16; ++q) {
            float m = MEMb[mbase + hq * 16 + q];
            float ee = (&er[q >> 2].x)[q & 3];
            float vv = (&wv[q >> 2].x)[q & 3];
            float kk = (&kf[q >> 2].x)[q & 3];
            m = m * (1.f - wwn * ee) + wwn * vv;
            MEMb[mbase + hq * 16 + q] = m;
            dotp += kk * m;
            mnp += m * m;
          }
        }
        SCRb[ws2 * 128 + n] = dotp;
        SCRb[256 + ws2 * 128 + n] = mnp;
      }
      {
        const int m = s & 127, kh = s >> 7;
        const float* WWh = sm + L_WW + bl * 128 + kh * 64;
        const float* PRh = sm + L_PREC + bl * 128 + kh * 64;
        const float* RWh = sm + L_RW + bl * 128 + kh * 64;
        float wwm = (sm + L_WW + bl * 128)[m];
        float prn = (sm + L_PREC + bl * 128)[m];
        float bwp = 0.f, fwp = 0.f;
#pragma unroll
        for (int kq = 0; kq < 16; ++kq) {
          float4 ww4 = *(const float4*)(WWh + kq * 4);
          float4 pr4 = *(const float4*)(PRh + kq * 4);
          float4 rw4 = *(const float4*)(RWh + kq * 4);
#pragma unroll
          for (int e = 0; e < 4; ++e) {
            int k = kq * 4 + e;
            int nn = kh * 64 + k;
            float wwo = (&ww4.x)[e];
            float pro = (&pr4.x)[e];
            float rwo = (&rw4.x)[e];
            float L = regL[k];
            L = (1.f - wwo - wwm) * L + pro * wwm;
            if (nn == m) L = 0.f;
            regL[k] = L;
            bwp += L * rwo;
            float LT = regLT[k];
            LT = (1.f - wwm - wwo) * LT + prn * wwo;
            if (nn == m) LT = 0.f;
            regLT[k] = LT;
            fwp += LT * rwo;
          }
        }
        SCRb[512 + kh * 128 + m] = bwp;
        SCRb[768 + kh * 128 + m] = fwp;
      }
    }
    __syncthreads();
    // ---- E4: softmax + combine + normalize (64 thr per batch)
    if (tid < 128) {
      const int bl = tid >> 6, li = tid & 63;
      const float* SCRb = sm + L_SCR + bl * 1024;
      int i0 = 2 * li, i1 = i0 + 1;
      float d0 = SCRb[i0] + SCRb[128 + i0];
      float d1 = SCRb[i1] + SCRb[128 + i1];
      float mn0 = sqrtf(SCRb[256 + i0] + SCRb[384 + i0]) + 1e-8f;
      float mn1 = sqrtf(SCRb[256 + i1] + SCRb[384 + i1]) + 1e-8f;
      float bw0 = SCRb[512 + i0] + SCRb[640 + i0];
      float bw1 = SCRb[512 + i1] + SCRb[640 + i1];
      float fw0 = SCRb[768 + i0] + SCRb[896 + i0];
      float fw1 = SCRb[768 + i1] + SCRb[896 + i1];
      float q0 = d0 / (kn_r * mn0) * rstr_r;
      float q1 = d1 / (kn_r * mn1) * rstr_r;
      float mx = fmaxf(q0, q1);
#pragma unroll
      for (int off = 32; off > 0; off >>= 1) mx = fmaxf(mx, __shfl_xor(mx, off, 64));
      float e0 = expf(q0 - mx), e1 = expf(q1 - mx);
      float es = e0 + e1;
#pragma unroll
      for (int off = 32; off > 0; off >>= 1) es += __shfl_xor(es, off, 64);
      float wv0 = rm0_r * bw0 + rm1_r * fw0 + rm2_r * (e0 / es) + 1e-8f;
      float wv1 = rm0_r * bw1 + rm1_r * fw1 + rm2_r * (e1 / es) + 1e-8f;
      float wsum = wv0 + wv1;
#pragma unroll
      for (int off = 32; off > 0; off >>= 1) wsum += __shfl_xor(wsum, off, 64);
      sm[L_RW + bl * 128 + i0] = wv0 / wsum;
      sm[L_RW + bl * 128 + i1] = wv1 / wsum;
    }
    __syncthreads();
    // ---- E5: rvec partials (256 thr per batch: 4 n-slices of 32)
    {
      const int bl = tid >> 8, s = tid & 255;
      const int w = s & 63, ns4 = s >> 6;
      const float* MEMb = sm + L_MEM + bl * 8320;
      const float* RWb = sm + L_RW + bl * 128;
      float* SCRb = sm + L_SCR + bl * 1024;
      float4 rw4[8];
#pragma unroll
      for (int r = 0; r < 8; ++r)
        rw4[r] = *(const float4*)(RWb + ns4 * 32 + r * 4);
      float p = 0.f;
#pragma unroll
      for (int k = 0; k < 32; ++k)
        p += (&rw4[k >> 2].x)[k & 3] * MEMb[(ns4 * 32 + k) * 65 + w];
      SCRb[ns4 * 64 + w] = p;
    }
    __syncthreads();
    // ---- E6: rvec reduce -> V | alloc(t+1) | prec update
    if (tid < 128) {               // rvec -> V rows 576.. (LOCAL, no publish!)
      const int bl = tid >> 6, w = tid & 63;
      const float* SCRb = sm + L_SCR + bl * 1024;
      float r = SCRb[w] + SCRb[64 + w] + SCRb[128 + w] + SCRb[192 + w];
      sm[L_V + (576 + w) * 2 + bl] = r;
    } else if (tid < 256) {        // next step's alloc from usage(t)
      const int bl = (tid >> 6) & 1, li = tid & 63, i0 = 2 * li, i1 = i0 + 1;
      float* USb = sm + L_USAGE + bl * 128;
      float* SSb = sm + L_SS + bl * 128;
      float* SCb = sm + L_SCAN + bl * 128;
      float* ALb = sm + L_ALLOC + bl * 128;
      float u0 = USb[i0], u1 = USb[i1];
      int r0 = 0, r1 = 0;
      for (int jc = 0; jc < 32; ++jc) {
        float4 uj4 = *(const float4*)(USb + jc * 4);
#pragma unroll
        for (int e = 0; e < 4; ++e) {
          float uj = (&uj4.x)[e];
          int j = jc * 4 + e;
          r0 += (uj < u0 || (uj == u0 && j < i0)) ? 1 : 0;
          r1 += (uj < u1 || (uj == u1 && j < i1)) ? 1 : 0;
        }
      }
      SSb[r0] = u0;
      SSb[r1] = u1;
      float s0 = SSb[i0], s1 = SSb[i1];
      float p = s0 * s1;
#pragma unroll
      for (int off = 1; off < 64; off <<= 1) {
        float v = __shfl_up(p, off, 64);
        if (li >= off) p *= v;
      }
      float E = __shfl_up(p, 1, 64);
      if (li == 0) E = 1.f;
      SCb[i0] = E * s0;
      SCb[i1] = E * s0 * s1;
      float ex0 = (r0 > 0) ? SCb[r0 - 1] : 1.f;
      float ex1 = (r1 > 0) ? SCb[r1 - 1] : 1.f;
      ALb[i0] = (1.f - u0) * ex0;
      ALb[i1] = (1.f - u1) * ex1;
    } else {                       // prec update
      const int bl = (tid >> 7) & 1, n = tid & 127;
      float wws = sm[L_SCAL + bl * 16];
      sm[L_PREC + bl * 128 + n] =
          (1.f - wws) * sm[L_PREC + bl * 128 + n] + sm[L_WW + bl * 128 + n];
    }
    __syncthreads();
  }
  // ---- epilogue: stage h(Tt-1) and emit out(Tt-1)
  {
    const u64* hsrc = g_h64 + (size_t)((Tt + 1) & 1) * (Bb * Hh);
    const int u = tid;
    const u64* a0 = hsrc + (size_t)b0 * Hh + u;
    const u64* a1 = hsrc + (size_t)(b0 + 1) * Hh + u;
    u64 v0 = ldrelax(a0), v1 = ldrelax(a1);
    float2 hh;
    hh.x = fixwait(a0, v0, (unsigned)Tt);
    hh.y = fixwait(a1, v1, (unsigned)Tt);
    *(float2*)(sm + L_V + u * 2) = hh;
  }
  __syncthreads();
  if (tid < 256) {
    const int g = tid >> 4, seg = tid & 15;
    const int o = jb * 8 + (g >> 1), bl = g & 1;
    const float4* w4 = (const float4*)(W_out + (size_t)o * 576) + seg * 9;
    float p = 0.f;
#pragma unroll
    for (int q = 0; q < 9; ++q) {
      float4 w = w4[q];
      int v = seg * 36 + q * 4;
      int r0 = (v < 512) ? v : v + 64;
      p += w.x * sm[L_V + (r0 + 0) * 2 + bl];
      p += w.y * sm[L_V + (r0 + 1) * 2 + bl];
      p += w.z * sm[L_V + (r0 + 2) * 2 + bl];
      p += w.w * sm[L_V + (r0 + 3) * 2 + bl];
    }
    p += __shfl_down(p, 8, 16);
    p += __shfl_down(p, 4, 16);
    p += __shfl_down(p, 2, 16);
    p += __shfl_down(p, 1, 16);
    if (seg == 0) out[((size_t)(b0 + bl) * Tt + (Tt - 1)) * Oo + o] = p + b_out[o];
  }
}

extern "C" void kernel_launch(void* const* d_in, const int* in_sizes, int n_in,
                              void* d_out, int out_size, void* d_ws, size_t ws_size,
                              hipStream_t stream) {
  (void)in_sizes; (void)n_in; (void)d_ws; (void)ws_size; (void)out_size;
  const float* x    = (const float*)d_in[0];
  const float* W_ih = (const float*)d_in[1];
  const float* W_hh = (const float*)d_in[2];
  const float* b_ih = (const float*)d_in[3];
  const float* b_hh = (const float*)d_in[4];
  const float* W_if = (const float*)d_in[5];
  const float* b_if = (const float*)d_in[6];
  const float* W_out = (const float*)d_in[7];
  const float* b_out = (const float*)d_in[8];
  float* out = (float*)d_out;

  dnc_init<<<320, TIN, 0, stream>>>(W_ih, W_hh, b_ih, b_hh);

  hipFuncSetAttribute((const void*)dnc_main,
                      hipFuncAttributeMaxDynamicSharedMemorySize, SMEM_BYTES);

  void* args[] = {(void*)&x, (void*)&W_if, (void*)&b_if,
                  (void*)&W_out, (void*)&b_out, (void*)&out};
  hipLaunchCooperativeKernel((void*)dnc_main, dim3(NWG), dim3(NT), args,
                             SMEM_BYTES, stream);
}

// Round 3
// 1643.708 us; speedup vs baseline: 1.2708x; 1.2708x over previous
//
#include <hip/hip_runtime.h>
#include <math.h>

// DNC: B=32,T=64,I=64,O=64,H=512,N=128,W=64,IF=198
// R16: one (batch, jb) pair per wg -> 256 wgs. Each wg: GEMV jb-slice for ONE
// batch + LSTM slice + itf partial + FULL local P2 (link state = 64 VGPRs,
// R14-proven, no spill). rvec is LDS-local (hop gone); h all-gather hidden
// behind own P2 chain; only exposed hop/step = itf all-gather (hidden partly
// under out(t-1)). wg%8=jb colocates weight-slice sharers per XCD.
#define Bb 32
#define Tt 64
#define Ii 64
#define Oo 64
#define Hh 512
#define Nn 128
#define Wd 64
#define IFs 198
#define KV 640
#define G4 2048

#define NWG 256
#define NT 512

// ---- LDS layout (float offsets), single batch per wg
#define L_WIF    0        /* 198*68 = 13464 */
#define L_BS     13464    /* 256 */
#define L_V      13720    /* 640 rows: [h 512 | x 64 | rvec 64] */
#define L_CC     14360    /* 64 */
#define L_HSL    14424    /* 64 */
#define L_BIF    14488    /* 224 */
#define L_ITF    14712    /* 224 */
#define L_ERASE  14936    /* 64 */
#define L_WVEC   15000    /* 64 */
#define L_USAGE  15064    /* 128 */
#define L_PREC   15192    /* 128 */
#define L_RW     15320    /* 128 */
#define L_WW     15448    /* 128 */
#define L_SCAN   15576    /* 128 */
#define L_SS     15704    /* 128 */
#define L_ALLOC  15832    /* 128 */
#define L_SCAL   15960    /* 16 */
#define L_SCR    15976    /* 2048 */
#define L_PACC   18024    /* 16 rows x 65 float4 = 4160 */
#define L_MEM    22184    /* 128 x 65 = 8320 */
#define SMEM_FLOATS 30504 /* 122016 B */
#define SMEM_BYTES (SMEM_FLOATS * 4)

// WT row permutation: rows = [h(512) | x(64) | rvec(64)].
__device__ __align__(16) float g_WT[KV * G4];
__device__ __align__(16) float g_bsum[G4];
typedef unsigned long long u64;
// Tagged handoffs: u64 = (step_tag << 32) | float_bits. Relaxed agent atomics.
__device__ u64 g_h64[2 * Bb * Hh];   // h, step-parity double buffer, tag t+1
__device__ u64 g_if64[Bb * 8 * 200]; // itf partials [b][jb(8)][o pad200] tag t+1

__device__ __forceinline__ float sigf(float v) { return 1.f / (1.f + expf(-v)); }

__device__ __forceinline__ u64 ldrelax(const u64* p) {
  return __hip_atomic_load(p, __ATOMIC_RELAXED, __HIP_MEMORY_SCOPE_AGENT);
}
__device__ __forceinline__ void tstore(u64* p, unsigned tag, float v) {
  u64 val = ((u64)tag << 32) | (u64)__float_as_uint(v);
  __hip_atomic_store(p, val, __ATOMIC_RELAXED, __HIP_MEMORY_SCOPE_AGENT);
}
__device__ __forceinline__ float fixwait(const u64* p, u64 v, unsigned tag) {
  while ((unsigned)(v >> 32) != tag) {
    __builtin_amdgcn_s_sleep(1);
    v = ldrelax(p);
  }
  return __uint_as_float((unsigned)(v & 0xffffffffu));
}

#define TIN 512
__global__ __launch_bounds__(TIN) void dnc_init(const float* __restrict__ W_ih,
                                                const float* __restrict__ W_hh,
                                                const float* __restrict__ b_ih,
                                                const float* __restrict__ b_hh) {
  __shared__ float tile[64][65];
  const int tid = threadIdx.x;
  int i0 = blockIdx.x * blockDim.x + tid;
  int st = gridDim.x * blockDim.x;
  for (int idx = i0; idx < G4; idx += st) g_bsum[idx] = b_ih[idx] + b_hh[idx];
  for (int idx = i0; idx < 2 * Bb * Hh; idx += st) g_h64[idx] = 0ull;
  for (int idx = i0; idx < Bb * 8 * 200; idx += st) g_if64[idx] = 0ull;

  for (int tileId = blockIdx.x; tileId < 320; tileId += gridDim.x) {
    int tc = tileId >> 5, tj = tileId & 31;
    for (int k = tid; k < 64 * 64; k += TIN) {
      int r = k >> 6, cl = k & 63;
      int j = tj * 64 + r, c = tc * 64 + cl;
      tile[r][cl] = (c < 128) ? W_ih[j * 128 + c] : W_hh[j * 512 + (c - 128)];
    }
    __syncthreads();
    for (int k = tid; k < 64 * 64; k += TIN) {
      int cl = k >> 6, rjj = k & 63;
      int c = tc * 64 + cl;
      // rows: h u -> u ; x c -> 512+c ; rvec -> 576+(c-64)  (== 512+c)
      int rp = (c < 128) ? (512 + c) : (c - 128);
      g_WT[(size_t)rp * G4 + tj * 64 + rjj] = tile[rjj][cl];
    }
    __syncthreads();
  }
}

__global__ __launch_bounds__(NT, 2) void dnc_main(const float* __restrict__ x,
                                                  const float* __restrict__ W_if,
                                                  const float* __restrict__ b_if,
                                                  const float* __restrict__ W_out,
                                                  const float* __restrict__ b_out,
                                                  float* __restrict__ out) {
  extern __shared__ float sm[];
  const int tid = threadIdx.x;
  const int wg = blockIdx.x;
  const int jb = wg & 7;
  const int b = wg >> 3;

  // link state: thread (m=tid&127, ks4=tid>>7) holds L[k,m]/LT[m,k] for
  // k in [ks4*32, ks4*32+32) — 64 VGPRs, the R14-proven no-spill budget.
  float regL[32], regLT[32];
#pragma unroll
  for (int k = 0; k < 32; ++k) { regL[k] = 0.f; regLT[k] = 0.f; }

  // ---- static init
  for (int i = tid; i < IFs * 64; i += NT) {
    int o = i >> 6, c = i & 63;
    sm[L_WIF + o * 68 + c] = W_if[(size_t)o * Hh + jb * 64 + c];
  }
  if (tid < 64) {
    int gq = tid >> 4, m = tid & 15;
    ((float4*)(sm + L_BS))[tid] = ((const float4*)g_bsum)[gq * 128 + jb * 16 + m];
    sm[L_CC + tid] = 0.f;
    sm[L_V + 576 + tid] = 0.f;  // rvec(-1) = 0
  }
  if (tid < IFs) sm[L_BIF + tid] = b_if[tid];
  if (tid < 128) {
    sm[L_USAGE + tid] = 0.f;
    sm[L_PREC + tid] = 0.f;
    sm[L_RW + tid] = 0.f;
  }
  for (int i = tid; i < Nn * 65; i += NT) sm[L_MEM + i] = 0.f;
  __syncthreads();
  // prologue: alloc for t=0 from usage=0
  if (tid < 64) {
    const int li = tid, i0 = 2 * li, i1 = i0 + 1;
    float u0 = sm[L_USAGE + i0], u1 = sm[L_USAGE + i1];
    int r0 = 0, r1 = 0;
    for (int jc = 0; jc < 32; ++jc) {
      float4 uj4 = *(const float4*)(sm + L_USAGE + jc * 4);
#pragma unroll
      for (int e = 0; e < 4; ++e) {
        float uj = (&uj4.x)[e];
        int j = jc * 4 + e;
        r0 += (uj < u0 || (uj == u0 && j < i0)) ? 1 : 0;
        r1 += (uj < u1 || (uj == u1 && j < i1)) ? 1 : 0;
      }
    }
    sm[L_SS + r0] = u0;
    sm[L_SS + r1] = u1;
    float s0 = sm[L_SS + i0], s1 = sm[L_SS + i1];
    float p = s0 * s1;
#pragma unroll
    for (int off = 1; off < 64; off <<= 1) {
      float v = __shfl_up(p, off, 64);
      if (li >= off) p *= v;
    }
    float E = __shfl_up(p, 1, 64);
    if (li == 0) E = 1.f;
    sm[L_SCAN + i0] = E * s0;
    sm[L_SCAN + i1] = E * s0 * s1;
    float ex0 = (r0 > 0) ? sm[L_SCAN + r0 - 1] : 1.f;
    float ex1 = (r1 > 0) ? sm[L_SCAN + r1 - 1] : 1.f;
    sm[L_ALLOC + i0] = (1.f - u0) * ex0;
    sm[L_ALLOC + i1] = (1.f - u1) * ex1;
  }
  __syncthreads();

  for (int t = 0; t < Tt; ++t) {
    // ---- A: stage h(t-1) (tagged gather; hits immediately — siblings
    //         published before our P2 chain finished) + x(t)
    {
      const u64* a0 = g_h64 + (size_t)((t + 1) & 1) * (Bb * Hh) + (size_t)b * Hh + tid;
      u64 v0 = ldrelax(a0);
      sm[L_V + tid] = fixwait(a0, v0, (unsigned)t);
      if (tid < 64) sm[L_V + 512 + tid] = x[((size_t)b * Tt + t) * Ii + tid];
    }
    __syncthreads();
    // ---- B: GEMV, 640 rows x 64 gate-cols (one batch). 16 ks x 40 rows.
    {
      const int fg = tid & 31, ks = tid >> 5;
      const int fcolA = ((fg >> 4) * 128) + jb * 16 + (fg & 15);  // gates 0,1
      const float* va = sm + L_V + ks * 40;
      const float4* wpA = (const float4*)g_WT + (size_t)(ks * 40) * 512 + fcolA;
      float4 aA = {0.f, 0.f, 0.f, 0.f}, aB = {0.f, 0.f, 0.f, 0.f};
#pragma unroll 4
      for (int r = 0; r < 40; ++r) {
        float4 wA = wpA[(size_t)r * 512];
        float4 wB = wpA[(size_t)r * 512 + 256];  // gates 2,3
        float fv = va[r];
        aA.x += wA.x * fv; aA.y += wA.y * fv; aA.z += wA.z * fv; aA.w += wA.w * fv;
        aB.x += wB.x * fv; aB.y += wB.y * fv; aB.z += wB.z * fv; aB.w += wB.w * fv;
      }
      float4* pacc = (float4*)(sm + L_PACC);
      pacc[ks * 65 + fg] = aA;
      pacc[ks * 65 + fg + 32] = aB;
    }
    __syncthreads();
    // ---- C: K-reduce (16 partials) + LSTM; publish h slice
    if (tid < 64) {
      const int l = tid;
      const float* pb = sm + L_PACC + l;
      float gv0 = 0.f, gv1 = 0.f, gv2 = 0.f, gv3 = 0.f;
#pragma unroll
      for (int ks = 0; ks < 16; ++ks) {
        const float* pk = pb + ks * 260;
        gv0 += pk[0];
        gv1 += pk[64];
        gv2 += pk[128];
        gv3 += pk[192];
      }
      float ig = gv0 + sm[L_BS + l];
      float fg = gv1 + sm[L_BS + 64 + l];
      float gg = gv2 + sm[L_BS + 128 + l];
      float og = gv3 + sm[L_BS + 192 + l];
      float co = sm[L_CC + l];
      float cn = sigf(fg) * co + sigf(ig) * tanhf(gg);
      float hn = sigf(og) * tanhf(cn);
      sm[L_CC + l] = cn;
      sm[L_HSL + l] = hn;
      tstore(g_h64 + (size_t)(t & 1) * (Bb * Hh) + (size_t)b * Hh + jb * 64 + l,
             (unsigned)(t + 1), hn);
    }
    __syncthreads();
    // ---- C2: itf partial publish; issue all-gather polls; hide the hop
    //          under out(t-1); gather.
    if (tid < 2 * IFs) {
      const int o = tid >> 1, hf = tid & 1;
      const float4* wr = (const float4*)(sm + L_WIF + o * 68) + hf * 8;
      const float4* h4 = (const float4*)(sm + L_HSL) + hf * 8;
      float acc = 0.f;
#pragma unroll
      for (int c4 = 0; c4 < 8; ++c4) {
        float4 w = wr[c4]; float4 h = h4[c4];
        acc += w.x * h.x + w.y * h.y + w.z * h.z + w.w * h.w;
      }
      acc += __shfl_xor(acc, 1, 64);
      if (hf == 0)
        tstore(g_if64 + ((size_t)b * 8 + jb) * 200 + o, (unsigned)(t + 1), acc);
    }
    const u64 *pp0, *pp1, *pp2, *pp3;
    u64 pv0 = 0, pv1 = 0, pv2 = 0, pv3 = 0;
    if (tid < 2 * IFs) {
      const int o = tid >> 1, hf = tid & 1;
      const u64* base = g_if64 + (size_t)b * 8 * 200 + (size_t)hf * 4 * 200 + o;
      pp0 = base; pp1 = base + 200; pp2 = base + 400; pp3 = base + 600;
      pv0 = ldrelax(pp0); pv1 = ldrelax(pp1); pv2 = ldrelax(pp2); pv3 = ldrelax(pp3);
    }
    if (t > 0 && tid >= 448) {  // out(t-1): staged h(t-1) + local rvec(t-1)
      const int o8 = (tid - 448) >> 3, seg = tid & 7;
      const int o = jb * 8 + o8;
      const float4* w4 = (const float4*)(W_out + (size_t)o * 576) + seg * 18;
      float p = 0.f;
#pragma unroll
      for (int q = 0; q < 18; ++q) {
        float4 w = w4[q];
        int v = seg * 72 + q * 4;
        int r0 = (v < 512) ? v : v + 64;  // skip x rows; rvec at 576+
        p += w.x * sm[L_V + r0] + w.y * sm[L_V + r0 + 1]
           + w.z * sm[L_V + r0 + 2] + w.w * sm[L_V + r0 + 3];
      }
      p += __shfl_down(p, 4, 8);
      p += __shfl_down(p, 2, 8);
      p += __shfl_down(p, 1, 8);
      if (seg == 0) out[((size_t)b * Tt + (t - 1)) * Oo + o] = p + b_out[o];
    }
    if (tid < 2 * IFs) {
      const int o = tid >> 1, hf = tid & 1;
      float s = fixwait(pp0, pv0, (unsigned)(t + 1))
              + fixwait(pp1, pv1, (unsigned)(t + 1))
              + fixwait(pp2, pv2, (unsigned)(t + 1))
              + fixwait(pp3, pv3, (unsigned)(t + 1));
      s += __shfl_xor(s, 1, 64);
      if (hf == 0) sm[L_ITF + o] = s + sm[L_BIF + o];
    }
    __syncthreads();
    // ---- E2: scalars + ww + usage (wave 0)
    float kn_r = 0.f, rstr_r = 0.f, rm0_r = 0.f, rm1_r = 0.f, rm2_r = 0.f;
    if (tid < 64) {
      const int li = tid, i0 = 2 * li, i1 = i0 + 1;
      float wgag = sigf(sm[L_ITF + 128]) * sigf(sm[L_ITF + 129]);
      float rs = sm[L_ITF + 194];
      rstr_r = (rs > 20.f) ? rs : log1pf(expf(rs));
      float m0 = sm[L_ITF + 195], m1 = sm[L_ITF + 196], m2 = sm[L_ITF + 197];
      float mx = fmaxf(m0, fmaxf(m1, m2));
      float e0 = expf(m0 - mx), e1 = expf(m1 - mx), e2 = expf(m2 - mx);
      float es = e0 + e1 + e2;
      rm0_r = e0 / es; rm1_r = e1 / es; rm2_r = e2 / es;
      float rk = sm[L_ITF + li];
      sm[L_ERASE + li] = sigf(rk);
      sm[L_WVEC + li] = sm[L_ITF + 64 + li];
      float sq = rk * rk;
#pragma unroll
      for (int off = 32; off > 0; off >>= 1) sq += __shfl_xor(sq, off, 64);
      kn_r = sqrtf(sq) + 1e-8f;
      float u0 = sm[L_USAGE + i0], u1 = sm[L_USAGE + i1];
      float w0 = wgag * sm[L_ALLOC + i0];
      float w1 = wgag * sm[L_ALLOC + i1];
      sm[L_WW + i0] = w0; sm[L_WW + i1] = w1;
      sm[L_USAGE + i0] = u0 + (1.f - u0) * w0;
      sm[L_USAGE + i1] = u1 + (1.f - u1) * w1;
      float wws = w0 + w1;
#pragma unroll
      for (int off = 32; off > 0; off >>= 1) wws += __shfl_xor(wws, off, 64);
      if (li == 0) sm[L_SCAL] = wws;
    }
    __syncthreads();
    // ---- E3: mem update + dot/mn + register link + bw/fw (512 thr)
    {
      float* SCR = sm + L_SCR;
      const int n = tid & 127, ws = tid >> 7;
      float4 er[4], wv[4], kf[4];
#pragma unroll
      for (int r = 0; r < 4; ++r) {
        er[r] = *(const float4*)(sm + L_ERASE + ws * 16 + r * 4);
        wv[r] = *(const float4*)(sm + L_WVEC + ws * 16 + r * 4);
        kf[r] = *(const float4*)(sm + L_ITF + ws * 16 + r * 4);
      }
      float wwn = sm[L_WW + n];
      float dotp = 0.f, mnp = 0.f;
      const int base = L_MEM + n * 65 + ws * 16;
#pragma unroll
      for (int q = 0; q < 16; ++q) {
        float m = sm[base + q];
        float ee = (&er[q >> 2].x)[q & 3];
        float vv = (&wv[q >> 2].x)[q & 3];
        float kk = (&kf[q >> 2].x)[q & 3];
        m = m * (1.f - wwn * ee) + wwn * vv;
        sm[base + q] = m;
        dotp += kk * m;
        mnp += m * m;
      }
      SCR[ws * 128 + n] = dotp;
      SCR[512 + ws * 128 + n] = mnp;
      const int m = n, ns = ws;
      float wwm = wwn;
      float prn = sm[L_PREC + m];
      float bwp = 0.f, fwp = 0.f;
#pragma unroll
      for (int kq = 0; kq < 8; ++kq) {
        float4 ww4 = *(const float4*)(sm + L_WW + ns * 32 + kq * 4);
        float4 pr4 = *(const float4*)(sm + L_PREC + ns * 32 + kq * 4);
        float4 rw4 = *(const float4*)(sm + L_RW + ns * 32 + kq * 4);
#pragma unroll
        for (int e = 0; e < 4; ++e) {
          int k = kq * 4 + e;
          int nn = ns * 32 + k;
          float wwo = (&ww4.x)[e];
          float pro = (&pr4.x)[e];
          float rwo = (&rw4.x)[e];
          float L = regL[k];
          L = (1.f - wwo - wwm) * L + pro * wwm;
          if (nn == m) L = 0.f;
          regL[k] = L;
          bwp += L * rwo;
          float LT = regLT[k];
          LT = (1.f - wwm - wwo) * LT + prn * wwo;
          if (nn == m) LT = 0.f;
          regLT[k] = LT;
          fwp += LT * rwo;
        }
      }
      SCR[1024 + ns * 128 + m] = bwp;
      SCR[1536 + ns * 128 + m] = fwp;
    }
    __syncthreads();
    // ---- E4: softmax + combine + normalize (wave 0)
    if (tid < 64) {
      float* SCR = sm + L_SCR;
      int i0 = 2 * tid, i1 = i0 + 1;
      float d0 = SCR[i0] + SCR[128 + i0] + SCR[256 + i0] + SCR[384 + i0];
      float d1 = SCR[i1] + SCR[128 + i1] + SCR[256 + i1] + SCR[384 + i1];
      float mn0 = sqrtf(SCR[512 + i0] + SCR[640 + i0] + SCR[768 + i0] + SCR[896 + i0]) + 1e-8f;
      float mn1 = sqrtf(SCR[512 + i1] + SCR[640 + i1] + SCR[768 + i1] + SCR[896 + i1]) + 1e-8f;
      float bw0 = SCR[1024 + i0] + SCR[1152 + i0] + SCR[1280 + i0] + SCR[1408 + i0];
      float bw1 = SCR[1024 + i1] + SCR[1152 + i1] + SCR[1280 + i1] + SCR[1408 + i1];
      float fw0 = SCR[1536 + i0] + SCR[1664 + i0] + SCR[1792 + i0] + SCR[1920 + i0];
      float fw1 = SCR[1536 + i1] + SCR[1664 + i1] + SCR[1792 + i1] + SCR[1920 + i1];
      float q0 = d0 / (kn_r * mn0) * rstr_r;
      float q1 = d1 / (kn_r * mn1) * rstr_r;
      float mx = fmaxf(q0, q1);
#pragma unroll
      for (int off = 32; off > 0; off >>= 1) mx = fmaxf(mx, __shfl_xor(mx, off, 64));
      float e0 = expf(q0 - mx), e1 = expf(q1 - mx);
      float es = e0 + e1;
#pragma unroll
      for (int off = 32; off > 0; off >>= 1) es += __shfl_xor(es, off, 64);
      float wv0 = rm0_r * bw0 + rm1_r * fw0 + rm2_r * (e0 / es) + 1e-8f;
      float wv1 = rm0_r * bw1 + rm1_r * fw1 + rm2_r * (e1 / es) + 1e-8f;
      float wsum = wv0 + wv1;
#pragma unroll
      for (int off = 32; off > 0; off >>= 1) wsum += __shfl_xor(wsum, off, 64);
      sm[L_RW + i0] = wv0 / wsum;
      sm[L_RW + i1] = wv1 / wsum;
    }
    __syncthreads();
    // ---- E5: rvec partials (8 n-slices of 16)
    {
      float* SCR = sm + L_SCR;
      const int w = tid & 63, ns8 = tid >> 6;
      float4 rw4[4];
#pragma unroll
      for (int r = 0; r < 4; ++r)
        rw4[r] = *(const float4*)(sm + L_RW + ns8 * 16 + r * 4);
      float p = 0.f;
#pragma unroll
      for (int k = 0; k < 16; ++k)
        p += (&rw4[k >> 2].x)[k & 3] * sm[L_MEM + (ns8 * 16 + k) * 65 + w];
      SCR[ns8 * 64 + w] = p;
    }
    __syncthreads();
    // ---- E6: rvec reduce -> V (LOCAL) | alloc(t+1) | prec update
    if (tid < 64) {
      const float* SCR = sm + L_SCR;
      float r = 0.f;
#pragma unroll
      for (int s2 = 0; s2 < 8; ++s2) r += SCR[s2 * 64 + tid];
      sm[L_V + 576 + tid] = r;
    } else if (tid < 128) {        // next step's alloc from usage(t): wave 1
      const int li = tid - 64, i0 = 2 * li, i1 = i0 + 1;
      float u0 = sm[L_USAGE + i0], u1 = sm[L_USAGE + i1];
      int r0 = 0, r1 = 0;
      for (int jc = 0; jc < 32; ++jc) {
        float4 uj4 = *(const float4*)(sm + L_USAGE + jc * 4);
#pragma unroll
        for (int e = 0; e < 4; ++e) {
          float uj = (&uj4.x)[e];
          int j = jc * 4 + e;
          r0 += (uj < u0 || (uj == u0 && j < i0)) ? 1 : 0;
          r1 += (uj < u1 || (uj == u1 && j < i1)) ? 1 : 0;
        }
      }
      sm[L_SS + r0] = u0;
      sm[L_SS + r1] = u1;
      float s0 = sm[L_SS + i0], s1 = sm[L_SS + i1];
      float p = s0 * s1;
#pragma unroll
      for (int off = 1; off < 64; off <<= 1) {
        float v = __shfl_up(p, off, 64);
        if (li >= off) p *= v;
      }
      float E = __shfl_up(p, 1, 64);
      if (li == 0) E = 1.f;
      sm[L_SCAN + i0] = E * s0;
      sm[L_SCAN + i1] = E * s0 * s1;
      float ex0 = (r0 > 0) ? sm[L_SCAN + r0 - 1] : 1.f;
      float ex1 = (r1 > 0) ? sm[L_SCAN + r1 - 1] : 1.f;
      sm[L_ALLOC + i0] = (1.f - u0) * ex0;
      sm[L_ALLOC + i1] = (1.f - u1) * ex1;
    } else if (tid < 256) {        // prec update
      const int n = tid - 128;     // 0..127
      float wws = sm[L_SCAL];
      sm[L_PREC + n] = (1.f - wws) * sm[L_PREC + n] + sm[L_WW + n];
    }
    __syncthreads();
  }
  // ---- epilogue: stage h(Tt-1) and emit out(Tt-1)
  {
    const u64* a0 = g_h64 + (size_t)((Tt + 1) & 1) * (Bb * Hh) + (size_t)b * Hh + tid;
    u64 v0 = ldrelax(a0);
    sm[L_V + tid] = fixwait(a0, v0, (unsigned)Tt);
  }
  __syncthreads();
  if (tid < 64) {
    const int o8 = tid >> 3, seg = tid & 7;
    const int o = jb * 8 + o8;
    const float4* w4 = (const float4*)(W_out + (size_t)o * 576) + seg * 18;
    float p = 0.f;
#pragma unroll
    for (int q = 0; q < 18; ++q) {
      float4 w = w4[q];
      int v = seg * 72 + q * 4;
      int r0 = (v < 512) ? v : v + 64;
      p += w.x * sm[L_V + r0] + w.y * sm[L_V + r0 + 1]
         + w.z * sm[L_V + r0 + 2] + w.w * sm[L_V + r0 + 3];
    }
    p += __shfl_down(p, 4, 8);
    p += __shfl_down(p, 2, 8);
    p += __shfl_down(p, 1, 8);
    if (seg == 0) out[((size_t)b * Tt + (Tt - 1)) * Oo + o] = p + b_out[o];
  }
}

extern "C" void kernel_launch(void* const* d_in, const int* in_sizes, int n_in,
                              void* d_out, int out_size, void* d_ws, size_t ws_size,
                              hipStream_t stream) {
  (void)in_sizes; (void)n_in; (void)d_ws; (void)ws_size; (void)out_size;
  const float* x    = (const float*)d_in[0];
  const float* W_ih = (const float*)d_in[1];
  const float* W_hh = (const float*)d_in[2];
  const float* b_ih = (const float*)d_in[3];
  const float* b_hh = (const float*)d_in[4];
  const float* W_if = (const float*)d_in[5];
  const float* b_if = (const float*)d_in[6];
  const float* W_out = (const float*)d_in[7];
  const float* b_out = (const float*)d_in[8];
  float* out = (float*)d_out;

  dnc_init<<<320, TIN, 0, stream>>>(W_ih, W_hh, b_ih, b_hh);

  hipFuncSetAttribute((const void*)dnc_main,
                      hipFuncAttributeMaxDynamicSharedMemorySize, SMEM_BYTES);

  void* args[] = {(void*)&x, (void*)&W_if, (void*)&b_if,
                  (void*)&W_out, (void*)&b_out, (void*)&out};
  hipLaunchCooperativeKernel((void*)dnc_main, dim3(NWG), dim3(NT), args,
                             SMEM_BYTES, stream);
}

// Round 4
// 960.641 us; speedup vs baseline: 2.1745x; 1.7111x over previous
//
#include <hip/hip_runtime.h>
#include <math.h>

// DNC: B=32,T=64,I=64,O=64,H=512,N=128,W=64,IF=198
// R17 = R14 (proven 804us) + P2 chain compression:
//  - E2 stage removed: ww computed inline from ALLOC(t) x wgag (alloc/allocsum
//    double-buffered by parity; usage/prec updates moved off-chain to E6').
//  - E4/E5/E6-rvec merged into ONE phase (E45'): every wave redundantly does
//    softmax+combine, shfl-distributes rw, computes 8 rvec cols via in-wave
//    tree reduce, and PUBLISHES rvec mid-phase. P2 on-chain barriers: 5 -> 2.
//  - h-gather / alloc(t+1) / prec / out-proj all run after the rvec publish,
//    hidden under P1's round trip.
#define Bb 32
#define Tt 64
#define Ii 64
#define Oo 64
#define Hh 512
#define Nn 128
#define Wd 64
#define IFs 198
#define KV 640
#define G4 2048

#define NP1 128          /* 16 bb-groups x 8 jb-slices */
#define NWG 160          /* + 32 P2 wgs */
#define NT 512

// ---- LDS layout (float offsets). P1/P2 blocks overlap (roles fixed per wg).
// P2 block:
#define P2_MEM    0        /* 128*65 = 8320 */
#define P2_H      8320     /* 576 [h|rvec] */
#define P2_SCR    8896     /* 2048 */
#define P2_ITF    10944    /* 224 */
#define P2_ERASE  11168    /* 64 */
#define P2_USAGE  11232    /* 128 */
#define P2_PREC   11360    /* 128 */
#define P2_RW     11488    /* 128 */
#define P2_SCAN   11616    /* 128 */
#define P2_SS     11744    /* 128 */
#define P2_SCAL   11872    /* 16: allocsum S[par] at [0],[1] */
#define P2_BIF    11888    /* 224 */
#define P2_ALLOC  12112    /* 2 x 128 (parity double buffer) */
// P1 block (W_if rows padded to 68):
#define P1_WIF    0        /* 198*68 = 13464 */
#define P1_BS     13464    /* 256 */
#define P1_V      13720    /* 640 rows x 2 batches interleaved = 1280 */
#define P1_CC     15016    /* 128 */
#define P1_HSL    15144    /* 128 */
#define P1_PACC   15272    /* 32*65 float4 = 8320 */
#define SMEM_FLOATS 23592  /* 94368 B */
#define SMEM_BYTES (SMEM_FLOATS * 4)

// WT row permutation: rows = [h(512) | x(64) | rvec(64)].
__device__ __align__(16) float g_WT[KV * G4];
__device__ __align__(16) float g_bsum[G4];
typedef unsigned long long u64;
// Tagged handoffs: u64 = (step_tag << 32) | float_bits. Relaxed agent atomics.
__device__ u64 g_h64[2 * Bb * Hh];   // h, step-parity double buffer, tag t+1
__device__ u64 g_rv64[Bb * Wd];      // rvec(t) tag t+1
__device__ u64 g_if64[Bb * 8 * 200]; // itf partials [b][jb(8)][o pad200] tag t+1

__device__ __forceinline__ float sigf(float v) { return 1.f / (1.f + expf(-v)); }

__device__ __forceinline__ u64 ldrelax(const u64* p) {
  return __hip_atomic_load(p, __ATOMIC_RELAXED, __HIP_MEMORY_SCOPE_AGENT);
}
__device__ __forceinline__ void tstore(u64* p, unsigned tag, float v) {
  u64 val = ((u64)tag << 32) | (u64)__float_as_uint(v);
  __hip_atomic_store(p, val, __ATOMIC_RELAXED, __HIP_MEMORY_SCOPE_AGENT);
}
__device__ __forceinline__ float fixwait(const u64* p, u64 v, unsigned tag) {
  while ((unsigned)(v >> 32) != tag) {
    __builtin_amdgcn_s_sleep(1);
    v = ldrelax(p);
  }
  return __uint_as_float((unsigned)(v & 0xffffffffu));
}

#define TIN 512
__global__ __launch_bounds__(TIN) void dnc_init(const float* __restrict__ W_ih,
                                                const float* __restrict__ W_hh,
                                                const float* __restrict__ b_ih,
                                                const float* __restrict__ b_hh) {
  __shared__ float tile[64][65];
  const int tid = threadIdx.x;
  int i0 = blockIdx.x * blockDim.x + tid;
  int st = gridDim.x * blockDim.x;
  for (int idx = i0; idx < G4; idx += st) g_bsum[idx] = b_ih[idx] + b_hh[idx];
  for (int idx = i0; idx < 2 * Bb * Hh; idx += st) g_h64[idx] = 0ull;
  for (int idx = i0; idx < Bb * Wd; idx += st) g_rv64[idx] = 0ull;
  for (int idx = i0; idx < Bb * 8 * 200; idx += st) g_if64[idx] = 0ull;

  for (int tileId = blockIdx.x; tileId < 320; tileId += gridDim.x) {
    int tc = tileId >> 5, tj = tileId & 31;
    for (int k = tid; k < 64 * 64; k += TIN) {
      int r = k >> 6, cl = k & 63;
      int j = tj * 64 + r, c = tc * 64 + cl;
      tile[r][cl] = (c < 128) ? W_ih[j * 128 + c] : W_hh[j * 512 + (c - 128)];
    }
    __syncthreads();
    for (int k = tid; k < 64 * 64; k += TIN) {
      int cl = k >> 6, rjj = k & 63;
      int c = tc * 64 + cl;
      // rows: h u -> u ; x c -> 512+c ; rvec -> 576+(c-64)  (== 512+c)
      int rp = (c < 128) ? (512 + c) : (c - 128);
      g_WT[(size_t)rp * G4 + tj * 64 + rjj] = tile[rjj][cl];
    }
    __syncthreads();
  }
}

__global__ __launch_bounds__(NT) void dnc_main(const float* __restrict__ x,
                                               const float* __restrict__ W_if,
                                               const float* __restrict__ b_if,
                                               const float* __restrict__ W_out,
                                               const float* __restrict__ b_out,
                                               float* __restrict__ out) {
  extern __shared__ float sm[];
  const int tid = threadIdx.x;
  const int wg = blockIdx.x;

  if (wg < NP1) {
    // ======================= P1: gates GEMV + fused LSTM + itf partials
    // (verbatim R14 — measured 804us steady; GEMV main body off-chain)
    const int jb = wg & 7;
    const int bb = wg >> 3;
    const int b0 = bb * 2;
    for (int i = tid; i < IFs * 64; i += NT) {
      int o = i >> 6, c = i & 63;
      sm[P1_WIF + o * 68 + c] = W_if[(size_t)o * Hh + jb * 64 + c];
    }
    if (tid < 64) {
      int gq = tid >> 4, m = tid & 15;
      ((float4*)(sm + P1_BS))[tid] = ((const float4*)g_bsum)[gq * 128 + jb * 16 + m];
    }
    if (tid < 128) sm[P1_CC + tid] = 0.f;
    __syncthreads();

    for (int t = 0; t < Tt; ++t) {
      {  // stage h(t-1) + x, batch-interleaved [row][bl]
        const u64* hsrc = g_h64 + (size_t)((t + 1) & 1) * (Bb * Hh);
        const int u = tid;
        const u64* a0 = hsrc + (size_t)b0 * Hh + u;
        const u64* a1 = hsrc + (size_t)(b0 + 1) * Hh + u;
        u64 v0 = ldrelax(a0), v1 = ldrelax(a1);
        float2 hh;
        hh.x = fixwait(a0, v0, (unsigned)t);
        hh.y = fixwait(a1, v1, (unsigned)t);
        *(float2*)(sm + P1_V + u * 2) = hh;
        if (tid < 128) {
          const int bl2 = tid >> 6, i = tid & 63;
          float xv = x[((size_t)(b0 + bl2) * Tt + t) * Ii + i];
          sm[P1_V + (512 + i) * 2 + bl2] = xv;
        }
      }
      __syncthreads();

      {  // GEMV: 640 rows split 16 ways; each weight loaded once.
        const int fg = tid & 31, ks = tid >> 5;  // ks 0..15, rows ks*40..+39
        const int fcolA = ((fg >> 4) * 128) + jb * 16 + (fg & 15);  // gates 0,1
        const float* v2 = sm + P1_V + ks * 80;
        const float4* wpA = (const float4*)g_WT + (size_t)(ks * 40) * 512 + fcolA;
        if (ks >= 14) {  // wave 7 owns rvec rows 576..639: tagged wait + stage
          const int j = tid & 63;
          const u64* r0 = g_rv64 + (size_t)b0 * Wd + j;
          const u64* r1 = g_rv64 + (size_t)(b0 + 1) * Wd + j;
          u64 u0 = ldrelax(r0), u1 = ldrelax(r1);
          float2 rv;
          rv.x = fixwait(r0, u0, (unsigned)t);
          rv.y = fixwait(r1, u1, (unsigned)t);
          *(float2*)(sm + P1_V + (576 + j) * 2) = rv;  // same-wave write->read
        }
        float4 aA0 = {0.f, 0.f, 0.f, 0.f}, aA1 = {0.f, 0.f, 0.f, 0.f};
        float4 aB0 = {0.f, 0.f, 0.f, 0.f}, aB1 = {0.f, 0.f, 0.f, 0.f};
#pragma unroll 4
        for (int r = 0; r < 40; ++r) {
          float4 wA = wpA[(size_t)r * 512];
          float4 wB = wpA[(size_t)r * 512 + 256];      // gates 2,3
          float2 vv = *(const float2*)(v2 + r * 2);
          aA0.x += wA.x * vv.x; aA0.y += wA.y * vv.x; aA0.z += wA.z * vv.x; aA0.w += wA.w * vv.x;
          aA1.x += wA.x * vv.y; aA1.y += wA.y * vv.y; aA1.z += wA.z * vv.y; aA1.w += wA.w * vv.y;
          aB0.x += wB.x * vv.x; aB0.y += wB.y * vv.x; aB0.z += wB.z * vv.x; aB0.w += wB.w * vv.x;
          aB1.x += wB.x * vv.y; aB1.y += wB.y * vv.y; aB1.z += wB.z * vv.y; aB1.w += wB.w * vv.y;
        }
        float4* pacc = (float4*)(sm + P1_PACC);
        pacc[(ks * 2 + 0) * 65 + fg] = aA0;
        pacc[(ks * 2 + 1) * 65 + fg] = aA1;
        pacc[(ks * 2 + 0) * 65 + fg + 32] = aB0;
        pacc[(ks * 2 + 1) * 65 + fg + 32] = aB1;
      }
      __syncthreads();
      if (tid < 128) {  // fused K-reduce (16 partials) + LSTM; h published tagged
        const int bl = tid >> 6, l = tid & 63;
        const float* pb = sm + P1_PACC + bl * 260 + l;
        float gv0 = 0.f, gv1 = 0.f, gv2 = 0.f, gv3 = 0.f;
#pragma unroll
        for (int ks = 0; ks < 16; ++ks) {
          const float* pk = pb + ks * 520;
          gv0 += pk[0];
          gv1 += pk[64];
          gv2 += pk[128];
          gv3 += pk[192];
        }
        float ig = gv0 + sm[P1_BS + l];
        float fg = gv1 + sm[P1_BS + 64 + l];
        float gg = gv2 + sm[P1_BS + 128 + l];
        float og = gv3 + sm[P1_BS + 192 + l];
        float co = sm[P1_CC + bl * 64 + l];
        float cn = sigf(fg) * co + sigf(ig) * tanhf(gg);
        float hn = sigf(og) * tanhf(cn);
        sm[P1_CC + bl * 64 + l] = cn;
        sm[P1_HSL + bl * 64 + l] = hn;
        tstore(g_h64 + (size_t)(t & 1) * (Bb * Hh) + (size_t)(b0 + bl) * Hh + jb * 64 + l,
               (unsigned)(t + 1), hn);
      }
      __syncthreads();
      if (tid < 2 * IFs) {  // itf partials from padded LDS W_if -> tagged stores
        const int o = tid >> 1, bl = tid & 1;
        const float4* wr = (const float4*)(sm + P1_WIF + o * 68);
        const float4* h4 = (const float4*)(sm + P1_HSL + bl * 64);
        float acc = 0.f;
#pragma unroll 8
        for (int c4 = 0; c4 < 16; ++c4) {
          float4 w = wr[c4]; float4 h = h4[c4];
          acc += w.x * h.x + w.y * h.y + w.z * h.z + w.w * h.w;
        }
        tstore(g_if64 + ((size_t)(b0 + bl) * 8 + jb) * 200 + o, (unsigned)(t + 1), acc);
      }
    }
  } else {
    // ======================= P2: DNC memory for batch b — 2 on-chain barriers
    const int b = wg - NP1;
    float* SCR = sm + P2_SCR;
    float regL[32], regLT[32];
#pragma unroll
    for (int k = 0; k < 32; ++k) { regL[k] = 0.f; regLT[k] = 0.f; }
    for (int i = tid; i < Nn * 65; i += NT) sm[P2_MEM + i] = 0.f;
    if (tid < 128) { sm[P2_USAGE + tid] = 0.f; sm[P2_PREC + tid] = 0.f; sm[P2_RW + tid] = 0.f; }
    if (tid < IFs) sm[P2_BIF + tid] = b_if[tid];
    __syncthreads();
    // prologue: alloc(0) from usage=0 -> ALLOC[0], allocsum -> S[0]
    if (tid < 64) {
      const int li = tid, i0 = 2 * li, i1 = i0 + 1;
      float u0 = sm[P2_USAGE + i0], u1 = sm[P2_USAGE + i1];
      int r0 = 0, r1 = 0;
      for (int jc = 0; jc < 32; ++jc) {
        float4 uj4 = *(const float4*)(sm + P2_USAGE + jc * 4);
#pragma unroll
        for (int e = 0; e < 4; ++e) {
          float uj = (&uj4.x)[e];
          int j = jc * 4 + e;
          r0 += (uj < u0 || (uj == u0 && j < i0)) ? 1 : 0;
          r1 += (uj < u1 || (uj == u1 && j < i1)) ? 1 : 0;
        }
      }
      sm[P2_SS + r0] = u0;
      sm[P2_SS + r1] = u1;
      float s0 = sm[P2_SS + i0], s1 = sm[P2_SS + i1];
      float p = s0 * s1;
#pragma unroll
      for (int off = 1; off < 64; off <<= 1) {
        float v = __shfl_up(p, off, 64);
        if (li >= off) p *= v;
      }
      float E = __shfl_up(p, 1, 64);
      if (li == 0) E = 1.f;
      sm[P2_SCAN + i0] = E * s0;
      sm[P2_SCAN + i1] = E * s0 * s1;
      float ex0 = (r0 > 0) ? sm[P2_SCAN + r0 - 1] : 1.f;
      float ex1 = (r1 > 0) ? sm[P2_SCAN + r1 - 1] : 1.f;
      float a0 = (1.f - u0) * ex0;
      float a1 = (1.f - u1) * ex1;
      sm[P2_ALLOC + i0] = a0;
      sm[P2_ALLOC + i1] = a1;
      float as = a0 + a1;
#pragma unroll
      for (int off = 32; off > 0; off >>= 1) as += __shfl_xor(as, off, 64);
      if (li == 0) sm[P2_SCAL + 0] = as;
    }
    __syncthreads();

    for (int t = 0; t < Tt; ++t) {
      // ---- phase 1: tagged itf gather (+ erase precompute)
      if (tid < 2 * IFs) {
        const int o = tid >> 1, hf = tid & 1;
        const u64* src = g_if64 + ((size_t)b * 8 + hf * 4) * 200 + o;
        u64 a0 = ldrelax(src), a1 = ldrelax(src + 200),
            a2 = ldrelax(src + 400), a3 = ldrelax(src + 600);
        float s = fixwait(src, a0, (unsigned)(t + 1))
                + fixwait(src + 200, a1, (unsigned)(t + 1))
                + fixwait(src + 400, a2, (unsigned)(t + 1))
                + fixwait(src + 600, a3, (unsigned)(t + 1));
        s += __shfl_xor(s, 1, 64);
        if (hf == 0) {
          float v = s + sm[P2_BIF + o];
          sm[P2_ITF + o] = v;
          if (o < 64) sm[P2_ERASE + o] = sigf(v);
        }
      }
      __syncthreads();
      // ---- phase 2 (E3'): mem+dot+mn + register link + bw/fw, ww INLINE
      {
        const int n = tid & 127, ws = tid >> 7;
        const float* ALo = sm + P2_ALLOC + (t & 1) * 128;
        const float wgag = sigf(sm[P2_ITF + 128]) * sigf(sm[P2_ITF + 129]);
        float4 er[4], wv[4], kf[4];
#pragma unroll
        for (int r = 0; r < 4; ++r) {
          er[r] = *(const float4*)(sm + P2_ERASE + ws * 16 + r * 4);
          wv[r] = *(const float4*)(sm + P2_ITF + 64 + ws * 16 + r * 4);
          kf[r] = *(const float4*)(sm + P2_ITF + ws * 16 + r * 4);
        }
        float wwn = wgag * ALo[n];
        float dotp = 0.f, mnp = 0.f;
        const int base = P2_MEM + n * 65 + ws * 16;
#pragma unroll
        for (int q = 0; q < 16; ++q) {
          float m = sm[base + q];
          float ee = (&er[q >> 2].x)[q & 3];
          float vv = (&wv[q >> 2].x)[q & 3];
          float kk = (&kf[q >> 2].x)[q & 3];
          m = m * (1.f - wwn * ee) + wwn * vv;
          sm[base + q] = m;
          dotp += kk * m;
          mnp += m * m;
        }
        SCR[ws * 128 + n] = dotp;
        SCR[512 + ws * 128 + n] = mnp;
        const int m = n, ns = ws;
        float wwm = wwn;
        float prn = sm[P2_PREC + m];
        float bwp = 0.f, fwp = 0.f;
#pragma unroll
        for (int kq = 0; kq < 8; ++kq) {
          float4 al4 = *(const float4*)(ALo + ns * 32 + kq * 4);
          float4 pr4 = *(const float4*)(sm + P2_PREC + ns * 32 + kq * 4);
          float4 rw4 = *(const float4*)(sm + P2_RW + ns * 32 + kq * 4);
#pragma unroll
          for (int e = 0; e < 4; ++e) {
            int k = kq * 4 + e;
            int nn = ns * 32 + k;
            float wwo = wgag * (&al4.x)[e];
            float pro = (&pr4.x)[e];
            float rwo = (&rw4.x)[e];
            float L = regL[k];
            L = (1.f - wwo - wwm) * L + pro * wwm;
            if (nn == m) L = 0.f;
            regL[k] = L;
            bwp += L * rwo;
            float LT = regLT[k];
            LT = (1.f - wwm - wwo) * LT + prn * wwo;
            if (nn == m) LT = 0.f;
            regLT[k] = LT;
            fwp += LT * rwo;
          }
        }
        SCR[1024 + ns * 128 + m] = bwp;
        SCR[1536 + ns * 128 + m] = fwp;
      }
      __syncthreads();
      // ---- phase 3 (E45'): per-wave redundant softmax+combine -> rw in regs
      //      -> shfl-distributed rvec MAC -> in-wave tree reduce -> PUBLISH.
      {
        const int l = tid & 63, wv8 = tid >> 6;
        float rs = sm[P2_ITF + 194];
        float rstr = (rs > 20.f) ? rs : log1pf(expf(rs));
        float m0 = sm[P2_ITF + 195], m1 = sm[P2_ITF + 196], m2 = sm[P2_ITF + 197];
        float mxm = fmaxf(m0, fmaxf(m1, m2));
        float e0m = expf(m0 - mxm), e1m = expf(m1 - mxm), e2m = expf(m2 - mxm);
        float esm = e0m + e1m + e2m;
        float rm0 = e0m / esm, rm1 = e1m / esm, rm2 = e2m / esm;
        float sq = 0.f;
#pragma unroll
        for (int c4 = 0; c4 < 16; ++c4) {
          float4 k4 = *(const float4*)(sm + P2_ITF + c4 * 4);
          sq += k4.x * k4.x + k4.y * k4.y + k4.z * k4.z + k4.w * k4.w;
        }
        float kn = sqrtf(sq) + 1e-8f;
        const int i0 = 2 * l, i1 = i0 + 1;
        float d0 = SCR[i0] + SCR[128 + i0] + SCR[256 + i0] + SCR[384 + i0];
        float d1 = SCR[i1] + SCR[128 + i1] + SCR[256 + i1] + SCR[384 + i1];
        float mn0 = sqrtf(SCR[512 + i0] + SCR[640 + i0] + SCR[768 + i0] + SCR[896 + i0]) + 1e-8f;
        float mn1 = sqrtf(SCR[512 + i1] + SCR[640 + i1] + SCR[768 + i1] + SCR[896 + i1]) + 1e-8f;
        float bw0 = SCR[1024 + i0] + SCR[1152 + i0] + SCR[1280 + i0] + SCR[1408 + i0];
        float bw1 = SCR[1024 + i1] + SCR[1152 + i1] + SCR[1280 + i1] + SCR[1408 + i1];
        float fw0 = SCR[1536 + i0] + SCR[1664 + i0] + SCR[1792 + i0] + SCR[1920 + i0];
        float fw1 = SCR[1536 + i1] + SCR[1664 + i1] + SCR[1792 + i1] + SCR[1920 + i1];
        float q0 = d0 / (kn * mn0) * rstr;
        float q1 = d1 / (kn * mn1) * rstr;
        float mx = fmaxf(q0, q1);
#pragma unroll
        for (int off = 32; off > 0; off >>= 1) mx = fmaxf(mx, __shfl_xor(mx, off, 64));
        float e0 = expf(q0 - mx), e1 = expf(q1 - mx);
        float es = e0 + e1;
#pragma unroll
        for (int off = 32; off > 0; off >>= 1) es += __shfl_xor(es, off, 64);
        float wv0 = rm0 * bw0 + rm1 * fw0 + rm2 * (e0 / es) + 1e-8f;
        float wv1 = rm0 * bw1 + rm1 * fw1 + rm2 * (e1 / es) + 1e-8f;
        float wsum = wv0 + wv1;
#pragma unroll
        for (int off = 32; off > 0; off >>= 1) wsum += __shfl_xor(wsum, off, 64);
        float rw0 = wv0 / wsum, rw1 = wv1 / wsum;
        if (wv8 == 0) { sm[P2_RW + i0] = rw0; sm[P2_RW + i1] = rw1; }
        // rvec: wave wv8 owns w = wv8*8 + (l>>3); lane group (l&7) covers 16 n
        const int w = wv8 * 8 + (l >> 3), n0 = (l & 7) * 16;
        float p = 0.f;
#pragma unroll
        for (int k = 0; k < 16; ++k) {
          int src = (l & 7) * 8 + (k >> 1);
          float rwk = (k & 1) ? __shfl(rw1, src, 64) : __shfl(rw0, src, 64);
          p += rwk * sm[P2_MEM + (n0 + k) * 65 + w];
        }
        p += __shfl_down(p, 4, 8);
        p += __shfl_down(p, 2, 8);
        p += __shfl_down(p, 1, 8);
        if ((l & 7) == 0) {  // chain exit: rvec(t) published here
          tstore(g_rv64 + (size_t)b * Wd + w, (unsigned)(t + 1), p);
          sm[P2_H + 512 + w] = p;
        }
      }
      __syncthreads();
      // ---- phase 4 (E6'): h gather | usage+alloc(t+1)+allocsum | prec
      if (tid < 256) {               // tagged h gather (off-chain)
        const u64* hsrc = g_h64 + (size_t)(t & 1) * (Bb * Hh) + (size_t)b * Hh;
        const u64* a0 = hsrc + tid * 2;
        const u64* a1 = hsrc + tid * 2 + 1;
        u64 v0 = ldrelax(a0), v1 = ldrelax(a1);
        sm[P2_H + tid * 2] = fixwait(a0, v0, (unsigned)(t + 1));
        sm[P2_H + tid * 2 + 1] = fixwait(a1, v1, (unsigned)(t + 1));
      } else if (tid < 320) {        // wave 4: usage(t) + alloc(t+1) + S
        const int li = tid - 256, i0 = 2 * li, i1 = i0 + 1;
        const float* ALo = sm + P2_ALLOC + (t & 1) * 128;
        float wgag = sigf(sm[P2_ITF + 128]) * sigf(sm[P2_ITF + 129]);
        float u0o = sm[P2_USAGE + i0], u1o = sm[P2_USAGE + i1];
        float u0 = u0o + (1.f - u0o) * (wgag * ALo[i0]);
        float u1 = u1o + (1.f - u1o) * (wgag * ALo[i1]);
        sm[P2_USAGE + i0] = u0;      // same-wave write->read (proven pattern)
        sm[P2_USAGE + i1] = u1;
        int r0 = 0, r1 = 0;
        for (int jc = 0; jc < 32; ++jc) {
          float4 uj4 = *(const float4*)(sm + P2_USAGE + jc * 4);
#pragma unroll
          for (int e = 0; e < 4; ++e) {
            float uj = (&uj4.x)[e];
            int j = jc * 4 + e;
            r0 += (uj < u0 || (uj == u0 && j < i0)) ? 1 : 0;
            r1 += (uj < u1 || (uj == u1 && j < i1)) ? 1 : 0;
          }
        }
        sm[P2_SS + r0] = u0;
        sm[P2_SS + r1] = u1;
        float s0 = sm[P2_SS + i0], s1 = sm[P2_SS + i1];
        float p = s0 * s1;
#pragma unroll
        for (int off = 1; off < 64; off <<= 1) {
          float v = __shfl_up(p, off, 64);
          if (li >= off) p *= v;
        }
        float E = __shfl_up(p, 1, 64);
        if (li == 0) E = 1.f;
        sm[P2_SCAN + i0] = E * s0;
        sm[P2_SCAN + i1] = E * s0 * s1;
        float ex0 = (r0 > 0) ? sm[P2_SCAN + r0 - 1] : 1.f;
        float ex1 = (r1 > 0) ? sm[P2_SCAN + r1 - 1] : 1.f;
        float a0 = (1.f - u0) * ex0;
        float a1 = (1.f - u1) * ex1;
        float* ALn = sm + P2_ALLOC + ((t + 1) & 1) * 128;
        ALn[i0] = a0;
        ALn[i1] = a1;
        float as = a0 + a1;
#pragma unroll
        for (int off = 32; off > 0; off >>= 1) as += __shfl_xor(as, off, 64);
        if (li == 0) sm[P2_SCAL + ((t + 1) & 1)] = as;
      } else if (tid < 448) {        // prec update (reads OLD-parity alloc/S)
        const int n = tid - 320;     // 0..127
        float wgag = sigf(sm[P2_ITF + 128]) * sigf(sm[P2_ITF + 129]);
        float wws = wgag * sm[P2_SCAL + (t & 1)];
        sm[P2_PREC + n] = (1.f - wws) * sm[P2_PREC + n]
                        + wgag * sm[P2_ALLOC + (t & 1) * 128 + n];
      }
      __syncthreads();
      // ---- phase 5: out projection (off-chain; no trailing barrier)
      {
        const int o = tid >> 3, seg = tid & 7;
        const float4* wrow = (const float4*)(W_out + (size_t)o * 576) + seg * 18;
        const float4* hb = (const float4*)(sm + P2_H) + seg * 18;
        float p = 0.f;
#pragma unroll
        for (int q = 0; q < 18; ++q) {
          float4 w = wrow[q]; float4 h = hb[q];
          p += w.x * h.x + w.y * h.y + w.z * h.z + w.w * h.w;
        }
        p += __shfl_down(p, 4, 8);
        p += __shfl_down(p, 2, 8);
        p += __shfl_down(p, 1, 8);
        if (seg == 0) out[((size_t)b * Tt + t) * Oo + o] = p + b_out[o];
      }
    }
  }
}

extern "C" void kernel_launch(void* const* d_in, const int* in_sizes, int n_in,
                              void* d_out, int out_size, void* d_ws, size_t ws_size,
                              hipStream_t stream) {
  (void)in_sizes; (void)n_in; (void)d_ws; (void)ws_size; (void)out_size;
  const float* x    = (const float*)d_in[0];
  const float* W_ih = (const float*)d_in[1];
  const float* W_hh = (const float*)d_in[2];
  const float* b_ih = (const float*)d_in[3];
  const float* b_hh = (const float*)d_in[4];
  const float* W_if = (const float*)d_in[5];
  const float* b_if = (const float*)d_in[6];
  const float* W_out = (const float*)d_in[7];
  const float* b_out = (const float*)d_in[8];
  float* out = (float*)d_out;

  dnc_init<<<320, TIN, 0, stream>>>(W_ih, W_hh, b_ih, b_hh);

  hipFuncSetAttribute((const void*)dnc_main,
                      hipFuncAttributeMaxDynamicSharedMemorySize, SMEM_BYTES);

  void* args[] = {(void*)&x, (void*)&W_if, (void*)&b_if,
                  (void*)&W_out, (void*)&b_out, (void*)&out};
  hipLaunchCooperativeKernel((void*)dnc_main, dim3(NWG), dim3(NT), args,
                             SMEM_BYTES, stream);
}

// Round 5
// 942.645 us; speedup vs baseline: 2.2160x; 1.0191x over previous
//
#include <hip/hip_runtime.h>
#include <math.h>

// DNC: B=32,T=64,I=64,O=64,H=512,N=128,W=64,IF=198
// R18 = R14 (proven 804us) + surgical P2 chain cuts (unbundled from R17):
//  - E2 removed: ww = wgag*ALLOC[parity] inline in E3 (R17-verified);
//    usage/alloc(t+1)/prec off-chain in E6' (R17-verified double buffer).
//  - E4 stays wave0-only (R17's per-wave redundant softmax REVERTED — it
//    added 3M bank conflicts + long shfl chains and cost 87us).
//  - E5/E6-rvec fused: per-wave column ownership, rw from LDS (broadcast),
//    in-wave 8-lane tree, immediate tagged publish. Chain barriers 5 -> 3.
#define Bb 32
#define Tt 64
#define Ii 64
#define Oo 64
#define Hh 512
#define Nn 128
#define Wd 64
#define IFs 198
#define KV 640
#define G4 2048

#define NP1 128          /* 16 bb-groups x 8 jb-slices */
#define NWG 160          /* + 32 P2 wgs */
#define NT 512

// ---- LDS layout (float offsets). P1/P2 blocks overlap (roles fixed per wg).
// P2 block:
#define P2_MEM    0        /* 128*65 = 8320 */
#define P2_H      8320     /* 576 [h|rvec] */
#define P2_SCR    8896     /* 2048 */
#define P2_ITF    10944    /* 224 */
#define P2_ERASE  11168    /* 64 */
#define P2_USAGE  11232    /* 128 */
#define P2_PREC   11360    /* 128 */
#define P2_RW     11488    /* 128 */
#define P2_SCAN   11616    /* 128 */
#define P2_SS     11744    /* 128 */
#define P2_SCAL   11872    /* 16: allocsum S[par] at [0],[1] */
#define P2_BIF    11888    /* 224 */
#define P2_ALLOC  12112    /* 2 x 128 (parity double buffer) */
// P1 block (W_if rows padded to 68):
#define P1_WIF    0        /* 198*68 = 13464 */
#define P1_BS     13464    /* 256 */
#define P1_V      13720    /* 640 rows x 2 batches interleaved = 1280 */
#define P1_CC     15016    /* 128 */
#define P1_HSL    15144    /* 128 */
#define P1_PACC   15272    /* 32*65 float4 = 8320 */
#define SMEM_FLOATS 23592  /* 94368 B */
#define SMEM_BYTES (SMEM_FLOATS * 4)

// WT row permutation: rows = [h(512) | x(64) | rvec(64)].
__device__ __align__(16) float g_WT[KV * G4];
__device__ __align__(16) float g_bsum[G4];
typedef unsigned long long u64;
// Tagged handoffs: u64 = (step_tag << 32) | float_bits. Relaxed agent atomics.
__device__ u64 g_h64[2 * Bb * Hh];   // h, step-parity double buffer, tag t+1
__device__ u64 g_rv64[Bb * Wd];      // rvec(t) tag t+1
__device__ u64 g_if64[Bb * 8 * 200]; // itf partials [b][jb(8)][o pad200] tag t+1

__device__ __forceinline__ float sigf(float v) { return 1.f / (1.f + expf(-v)); }

__device__ __forceinline__ u64 ldrelax(const u64* p) {
  return __hip_atomic_load(p, __ATOMIC_RELAXED, __HIP_MEMORY_SCOPE_AGENT);
}
__device__ __forceinline__ void tstore(u64* p, unsigned tag, float v) {
  u64 val = ((u64)tag << 32) | (u64)__float_as_uint(v);
  __hip_atomic_store(p, val, __ATOMIC_RELAXED, __HIP_MEMORY_SCOPE_AGENT);
}
__device__ __forceinline__ float fixwait(const u64* p, u64 v, unsigned tag) {
  while ((unsigned)(v >> 32) != tag) {
    __builtin_amdgcn_s_sleep(1);
    v = ldrelax(p);
  }
  return __uint_as_float((unsigned)(v & 0xffffffffu));
}

#define TIN 512
__global__ __launch_bounds__(TIN) void dnc_init(const float* __restrict__ W_ih,
                                                const float* __restrict__ W_hh,
                                                const float* __restrict__ b_ih,
                                                const float* __restrict__ b_hh) {
  __shared__ float tile[64][65];
  const int tid = threadIdx.x;
  int i0 = blockIdx.x * blockDim.x + tid;
  int st = gridDim.x * blockDim.x;
  for (int idx = i0; idx < G4; idx += st) g_bsum[idx] = b_ih[idx] + b_hh[idx];
  for (int idx = i0; idx < 2 * Bb * Hh; idx += st) g_h64[idx] = 0ull;
  for (int idx = i0; idx < Bb * Wd; idx += st) g_rv64[idx] = 0ull;
  for (int idx = i0; idx < Bb * 8 * 200; idx += st) g_if64[idx] = 0ull;

  for (int tileId = blockIdx.x; tileId < 320; tileId += gridDim.x) {
    int tc = tileId >> 5, tj = tileId & 31;
    for (int k = tid; k < 64 * 64; k += TIN) {
      int r = k >> 6, cl = k & 63;
      int j = tj * 64 + r, c = tc * 64 + cl;
      tile[r][cl] = (c < 128) ? W_ih[j * 128 + c] : W_hh[j * 512 + (c - 128)];
    }
    __syncthreads();
    for (int k = tid; k < 64 * 64; k += TIN) {
      int cl = k >> 6, rjj = k & 63;
      int c = tc * 64 + cl;
      // rows: h u -> u ; x c -> 512+c ; rvec -> 576+(c-64)  (== 512+c)
      int rp = (c < 128) ? (512 + c) : (c - 128);
      g_WT[(size_t)rp * G4 + tj * 64 + rjj] = tile[rjj][cl];
    }
    __syncthreads();
  }
}

__global__ __launch_bounds__(NT) void dnc_main(const float* __restrict__ x,
                                               const float* __restrict__ W_if,
                                               const float* __restrict__ b_if,
                                               const float* __restrict__ W_out,
                                               const float* __restrict__ b_out,
                                               float* __restrict__ out) {
  extern __shared__ float sm[];
  const int tid = threadIdx.x;
  const int wg = blockIdx.x;

  if (wg < NP1) {
    // ======================= P1: gates GEMV + fused LSTM + itf partials
    // (verbatim R14 — measured 804us steady; GEMV main body off-chain)
    const int jb = wg & 7;
    const int bb = wg >> 3;
    const int b0 = bb * 2;
    for (int i = tid; i < IFs * 64; i += NT) {
      int o = i >> 6, c = i & 63;
      sm[P1_WIF + o * 68 + c] = W_if[(size_t)o * Hh + jb * 64 + c];
    }
    if (tid < 64) {
      int gq = tid >> 4, m = tid & 15;
      ((float4*)(sm + P1_BS))[tid] = ((const float4*)g_bsum)[gq * 128 + jb * 16 + m];
    }
    if (tid < 128) sm[P1_CC + tid] = 0.f;
    __syncthreads();

    for (int t = 0; t < Tt; ++t) {
      {  // stage h(t-1) + x, batch-interleaved [row][bl]
        const u64* hsrc = g_h64 + (size_t)((t + 1) & 1) * (Bb * Hh);
        const int u = tid;
        const u64* a0 = hsrc + (size_t)b0 * Hh + u;
        const u64* a1 = hsrc + (size_t)(b0 + 1) * Hh + u;
        u64 v0 = ldrelax(a0), v1 = ldrelax(a1);
        float2 hh;
        hh.x = fixwait(a0, v0, (unsigned)t);
        hh.y = fixwait(a1, v1, (unsigned)t);
        *(float2*)(sm + P1_V + u * 2) = hh;
        if (tid < 128) {
          const int bl2 = tid >> 6, i = tid & 63;
          float xv = x[((size_t)(b0 + bl2) * Tt + t) * Ii + i];
          sm[P1_V + (512 + i) * 2 + bl2] = xv;
        }
      }
      __syncthreads();

      {  // GEMV: 640 rows split 16 ways; each weight loaded once.
        const int fg = tid & 31, ks = tid >> 5;  // ks 0..15, rows ks*40..+39
        const int fcolA = ((fg >> 4) * 128) + jb * 16 + (fg & 15);  // gates 0,1
        const float* v2 = sm + P1_V + ks * 80;
        const float4* wpA = (const float4*)g_WT + (size_t)(ks * 40) * 512 + fcolA;
        if (ks >= 14) {  // wave 7 owns rvec rows 576..639: tagged wait + stage
          const int j = tid & 63;
          const u64* r0 = g_rv64 + (size_t)b0 * Wd + j;
          const u64* r1 = g_rv64 + (size_t)(b0 + 1) * Wd + j;
          u64 u0 = ldrelax(r0), u1 = ldrelax(r1);
          float2 rv;
          rv.x = fixwait(r0, u0, (unsigned)t);
          rv.y = fixwait(r1, u1, (unsigned)t);
          *(float2*)(sm + P1_V + (576 + j) * 2) = rv;  // same-wave write->read
        }
        float4 aA0 = {0.f, 0.f, 0.f, 0.f}, aA1 = {0.f, 0.f, 0.f, 0.f};
        float4 aB0 = {0.f, 0.f, 0.f, 0.f}, aB1 = {0.f, 0.f, 0.f, 0.f};
#pragma unroll 4
        for (int r = 0; r < 40; ++r) {
          float4 wA = wpA[(size_t)r * 512];
          float4 wB = wpA[(size_t)r * 512 + 256];      // gates 2,3
          float2 vv = *(const float2*)(v2 + r * 2);
          aA0.x += wA.x * vv.x; aA0.y += wA.y * vv.x; aA0.z += wA.z * vv.x; aA0.w += wA.w * vv.x;
          aA1.x += wA.x * vv.y; aA1.y += wA.y * vv.y; aA1.z += wA.z * vv.y; aA1.w += wA.w * vv.y;
          aB0.x += wB.x * vv.x; aB0.y += wB.y * vv.x; aB0.z += wB.z * vv.x; aB0.w += wB.w * vv.x;
          aB1.x += wB.x * vv.y; aB1.y += wB.y * vv.y; aB1.z += wB.z * vv.y; aB1.w += wB.w * vv.y;
        }
        float4* pacc = (float4*)(sm + P1_PACC);
        pacc[(ks * 2 + 0) * 65 + fg] = aA0;
        pacc[(ks * 2 + 1) * 65 + fg] = aA1;
        pacc[(ks * 2 + 0) * 65 + fg + 32] = aB0;
        pacc[(ks * 2 + 1) * 65 + fg + 32] = aB1;
      }
      __syncthreads();
      if (tid < 128) {  // fused K-reduce (16 partials) + LSTM; h published tagged
        const int bl = tid >> 6, l = tid & 63;
        const float* pb = sm + P1_PACC + bl * 260 + l;
        float gv0 = 0.f, gv1 = 0.f, gv2 = 0.f, gv3 = 0.f;
#pragma unroll
        for (int ks = 0; ks < 16; ++ks) {
          const float* pk = pb + ks * 520;
          gv0 += pk[0];
          gv1 += pk[64];
          gv2 += pk[128];
          gv3 += pk[192];
        }
        float ig = gv0 + sm[P1_BS + l];
        float fg = gv1 + sm[P1_BS + 64 + l];
        float gg = gv2 + sm[P1_BS + 128 + l];
        float og = gv3 + sm[P1_BS + 192 + l];
        float co = sm[P1_CC + bl * 64 + l];
        float cn = sigf(fg) * co + sigf(ig) * tanhf(gg);
        float hn = sigf(og) * tanhf(cn);
        sm[P1_CC + bl * 64 + l] = cn;
        sm[P1_HSL + bl * 64 + l] = hn;
        tstore(g_h64 + (size_t)(t & 1) * (Bb * Hh) + (size_t)(b0 + bl) * Hh + jb * 64 + l,
               (unsigned)(t + 1), hn);
      }
      __syncthreads();
      if (tid < 2 * IFs) {  // itf partials from padded LDS W_if -> tagged stores
        const int o = tid >> 1, bl = tid & 1;
        const float4* wr = (const float4*)(sm + P1_WIF + o * 68);
        const float4* h4 = (const float4*)(sm + P1_HSL + bl * 64);
        float acc = 0.f;
#pragma unroll 8
        for (int c4 = 0; c4 < 16; ++c4) {
          float4 w = wr[c4]; float4 h = h4[c4];
          acc += w.x * h.x + w.y * h.y + w.z * h.z + w.w * h.w;
        }
        tstore(g_if64 + ((size_t)(b0 + bl) * 8 + jb) * 200 + o, (unsigned)(t + 1), acc);
      }
    }
  } else {
    // ======================= P2: DNC memory for batch b — 3 on-chain barriers
    const int b = wg - NP1;
    float* SCR = sm + P2_SCR;
    float regL[32], regLT[32];
#pragma unroll
    for (int k = 0; k < 32; ++k) { regL[k] = 0.f; regLT[k] = 0.f; }
    for (int i = tid; i < Nn * 65; i += NT) sm[P2_MEM + i] = 0.f;
    if (tid < 128) { sm[P2_USAGE + tid] = 0.f; sm[P2_PREC + tid] = 0.f; sm[P2_RW + tid] = 0.f; }
    if (tid < IFs) sm[P2_BIF + tid] = b_if[tid];
    __syncthreads();
    // prologue: alloc(0) from usage=0 -> ALLOC[0], allocsum -> S[0]
    if (tid < 64) {
      const int li = tid, i0 = 2 * li, i1 = i0 + 1;
      float u0 = sm[P2_USAGE + i0], u1 = sm[P2_USAGE + i1];
      int r0 = 0, r1 = 0;
      for (int jc = 0; jc < 32; ++jc) {
        float4 uj4 = *(const float4*)(sm + P2_USAGE + jc * 4);
#pragma unroll
        for (int e = 0; e < 4; ++e) {
          float uj = (&uj4.x)[e];
          int j = jc * 4 + e;
          r0 += (uj < u0 || (uj == u0 && j < i0)) ? 1 : 0;
          r1 += (uj < u1 || (uj == u1 && j < i1)) ? 1 : 0;
        }
      }
      sm[P2_SS + r0] = u0;
      sm[P2_SS + r1] = u1;
      float s0 = sm[P2_SS + i0], s1 = sm[P2_SS + i1];
      float p = s0 * s1;
#pragma unroll
      for (int off = 1; off < 64; off <<= 1) {
        float v = __shfl_up(p, off, 64);
        if (li >= off) p *= v;
      }
      float E = __shfl_up(p, 1, 64);
      if (li == 0) E = 1.f;
      sm[P2_SCAN + i0] = E * s0;
      sm[P2_SCAN + i1] = E * s0 * s1;
      float ex0 = (r0 > 0) ? sm[P2_SCAN + r0 - 1] : 1.f;
      float ex1 = (r1 > 0) ? sm[P2_SCAN + r1 - 1] : 1.f;
      float a0 = (1.f - u0) * ex0;
      float a1 = (1.f - u1) * ex1;
      sm[P2_ALLOC + i0] = a0;
      sm[P2_ALLOC + i1] = a1;
      float as = a0 + a1;
#pragma unroll
      for (int off = 32; off > 0; off >>= 1) as += __shfl_xor(as, off, 64);
      if (li == 0) sm[P2_SCAL + 0] = as;
    }
    __syncthreads();

    for (int t = 0; t < Tt; ++t) {
      // ---- phase 1: tagged itf gather (+ erase precompute)
      if (tid < 2 * IFs) {
        const int o = tid >> 1, hf = tid & 1;
        const u64* src = g_if64 + ((size_t)b * 8 + hf * 4) * 200 + o;
        u64 a0 = ldrelax(src), a1 = ldrelax(src + 200),
            a2 = ldrelax(src + 400), a3 = ldrelax(src + 600);
        float s = fixwait(src, a0, (unsigned)(t + 1))
                + fixwait(src + 200, a1, (unsigned)(t + 1))
                + fixwait(src + 400, a2, (unsigned)(t + 1))
                + fixwait(src + 600, a3, (unsigned)(t + 1));
        s += __shfl_xor(s, 1, 64);
        if (hf == 0) {
          float v = s + sm[P2_BIF + o];
          sm[P2_ITF + o] = v;
          if (o < 64) sm[P2_ERASE + o] = sigf(v);
        }
      }
      __syncthreads();
      // ---- phase 2 (E3): mem+dot+mn + register link + bw/fw, ww INLINE
      {
        const int n = tid & 127, ws = tid >> 7;
        const float* ALo = sm + P2_ALLOC + (t & 1) * 128;
        const float wgag = sigf(sm[P2_ITF + 128]) * sigf(sm[P2_ITF + 129]);
        float4 er[4], wv[4], kf[4];
#pragma unroll
        for (int r = 0; r < 4; ++r) {
          er[r] = *(const float4*)(sm + P2_ERASE + ws * 16 + r * 4);
          wv[r] = *(const float4*)(sm + P2_ITF + 64 + ws * 16 + r * 4);
          kf[r] = *(const float4*)(sm + P2_ITF + ws * 16 + r * 4);
        }
        float wwn = wgag * ALo[n];
        float dotp = 0.f, mnp = 0.f;
        const int base = P2_MEM + n * 65 + ws * 16;
#pragma unroll
        for (int q = 0; q < 16; ++q) {
          float m = sm[base + q];
          float ee = (&er[q >> 2].x)[q & 3];
          float vv = (&wv[q >> 2].x)[q & 3];
          float kk = (&kf[q >> 2].x)[q & 3];
          m = m * (1.f - wwn * ee) + wwn * vv;
          sm[base + q] = m;
          dotp += kk * m;
          mnp += m * m;
        }
        SCR[ws * 128 + n] = dotp;
        SCR[512 + ws * 128 + n] = mnp;
        const int m = n, ns = ws;
        float wwm = wwn;
        float prn = sm[P2_PREC + m];
        float bwp = 0.f, fwp = 0.f;
#pragma unroll
        for (int kq = 0; kq < 8; ++kq) {
          float4 al4 = *(const float4*)(ALo + ns * 32 + kq * 4);
          float4 pr4 = *(const float4*)(sm + P2_PREC + ns * 32 + kq * 4);
          float4 rw4 = *(const float4*)(sm + P2_RW + ns * 32 + kq * 4);
#pragma unroll
          for (int e = 0; e < 4; ++e) {
            int k = kq * 4 + e;
            int nn = ns * 32 + k;
            float wwo = wgag * (&al4.x)[e];
            float pro = (&pr4.x)[e];
            float rwo = (&rw4.x)[e];
            float L = regL[k];
            L = (1.f - wwo - wwm) * L + pro * wwm;
            if (nn == m) L = 0.f;
            regL[k] = L;
            bwp += L * rwo;
            float LT = regLT[k];
            LT = (1.f - wwm - wwo) * LT + prn * wwo;
            if (nn == m) LT = 0.f;
            regLT[k] = LT;
            fwp += LT * rwo;
          }
        }
        SCR[1024 + ns * 128 + m] = bwp;
        SCR[1536 + ns * 128 + m] = fwp;
      }
      __syncthreads();
      // ---- phase 3 (E4): wave0-only softmax + combine + normalize -> RW
      if (tid < 64) {
        const int li = tid;
        float rs = sm[P2_ITF + 194];
        float rstr = (rs > 20.f) ? rs : log1pf(expf(rs));
        float m0 = sm[P2_ITF + 195], m1 = sm[P2_ITF + 196], m2 = sm[P2_ITF + 197];
        float mxm = fmaxf(m0, fmaxf(m1, m2));
        float e0m = expf(m0 - mxm), e1m = expf(m1 - mxm), e2m = expf(m2 - mxm);
        float esm = e0m + e1m + e2m;
        float rm0 = e0m / esm, rm1 = e1m / esm, rm2 = e2m / esm;
        float sq = 0.f;
#pragma unroll
        for (int c4 = 0; c4 < 16; ++c4) {
          float4 k4 = *(const float4*)(sm + P2_ITF + c4 * 4);
          sq += k4.x * k4.x + k4.y * k4.y + k4.z * k4.z + k4.w * k4.w;
        }
        float kn = sqrtf(sq) + 1e-8f;
        int i0 = 2 * li, i1 = i0 + 1;
        float d0 = SCR[i0] + SCR[128 + i0] + SCR[256 + i0] + SCR[384 + i0];
        float d1 = SCR[i1] + SCR[128 + i1] + SCR[256 + i1] + SCR[384 + i1];
        float mn0 = sqrtf(SCR[512 + i0] + SCR[640 + i0] + SCR[768 + i0] + SCR[896 + i0]) + 1e-8f;
        float mn1 = sqrtf(SCR[512 + i1] + SCR[640 + i1] + SCR[768 + i1] + SCR[896 + i1]) + 1e-8f;
        float bw0 = SCR[1024 + i0] + SCR[1152 + i0] + SCR[1280 + i0] + SCR[1408 + i0];
        float bw1 = SCR[1024 + i1] + SCR[1152 + i1] + SCR[1280 + i1] + SCR[1408 + i1];
        float fw0 = SCR[1536 + i0] + SCR[1664 + i0] + SCR[1792 + i0] + SCR[1920 + i0];
        float fw1 = SCR[1536 + i1] + SCR[1664 + i1] + SCR[1792 + i1] + SCR[1920 + i1];
        float q0 = d0 / (kn * mn0) * rstr;
        float q1 = d1 / (kn * mn1) * rstr;
        float mx = fmaxf(q0, q1);
#pragma unroll
        for (int off = 32; off > 0; off >>= 1) mx = fmaxf(mx, __shfl_xor(mx, off, 64));
        float e0 = expf(q0 - mx), e1 = expf(q1 - mx);
        float es = e0 + e1;
#pragma unroll
        for (int off = 32; off > 0; off >>= 1) es += __shfl_xor(es, off, 64);
        float wv0 = rm0 * bw0 + rm1 * fw0 + rm2 * (e0 / es) + 1e-8f;
        float wv1 = rm0 * bw1 + rm1 * fw1 + rm2 * (e1 / es) + 1e-8f;
        float wsum = wv0 + wv1;
#pragma unroll
        for (int off = 32; off > 0; off >>= 1) wsum += __shfl_xor(wsum, off, 64);
        sm[P2_RW + i0] = wv0 / wsum;
        sm[P2_RW + i1] = wv1 / wsum;
      }
      __syncthreads();
      // ---- phase 4 (E5'): rvec per-wave columns + in-wave tree + PUBLISH.
      //      rw from LDS (broadcast), no shfl distribution, no extra barrier.
      {
        const int l = tid & 63, wv8 = tid >> 6;
        const int w = wv8 * 8 + (l >> 3), g = l & 7, n0 = g * 16;
        float p = 0.f;
#pragma unroll
        for (int k = 0; k < 16; ++k)
          p += sm[P2_RW + n0 + k] * sm[P2_MEM + (n0 + k) * 65 + w];
        p += __shfl_down(p, 4, 8);
        p += __shfl_down(p, 2, 8);
        p += __shfl_down(p, 1, 8);
        if (g == 0) {  // chain exit: rvec(t) published here
          tstore(g_rv64 + (size_t)b * Wd + w, (unsigned)(t + 1), p);
          sm[P2_H + 512 + w] = p;
        }
      }
      __syncthreads();
      // ---- phase 5 (E6'): h gather | usage+alloc(t+1)+allocsum | prec
      if (tid < 256) {               // tagged h gather (off-chain)
        const u64* hsrc = g_h64 + (size_t)(t & 1) * (Bb * Hh) + (size_t)b * Hh;
        const u64* a0 = hsrc + tid * 2;
        const u64* a1 = hsrc + tid * 2 + 1;
        u64 v0 = ldrelax(a0), v1 = ldrelax(a1);
        sm[P2_H + tid * 2] = fixwait(a0, v0, (unsigned)(t + 1));
        sm[P2_H + tid * 2 + 1] = fixwait(a1, v1, (unsigned)(t + 1));
      } else if (tid < 320) {        // wave 4: usage(t) + alloc(t+1) + S
        const int li = tid - 256, i0 = 2 * li, i1 = i0 + 1;
        const float* ALo = sm + P2_ALLOC + (t & 1) * 128;
        float wgag = sigf(sm[P2_ITF + 128]) * sigf(sm[P2_ITF + 129]);
        float u0o = sm[P2_USAGE + i0], u1o = sm[P2_USAGE + i1];
        float u0 = u0o + (1.f - u0o) * (wgag * ALo[i0]);
        float u1 = u1o + (1.f - u1o) * (wgag * ALo[i1]);
        sm[P2_USAGE + i0] = u0;      // same-wave write->read (R17-verified)
        sm[P2_USAGE + i1] = u1;
        int r0 = 0, r1 = 0;
        for (int jc = 0; jc < 32; ++jc) {
          float4 uj4 = *(const float4*)(sm + P2_USAGE + jc * 4);
#pragma unroll
          for (int e = 0; e < 4; ++e) {
            float uj = (&uj4.x)[e];
            int j = jc * 4 + e;
            r0 += (uj < u0 || (uj == u0 && j < i0)) ? 1 : 0;
            r1 += (uj < u1 || (uj == u1 && j < i1)) ? 1 : 0;
          }
        }
        sm[P2_SS + r0] = u0;
        sm[P2_SS + r1] = u1;
        float s0 = sm[P2_SS + i0], s1 = sm[P2_SS + i1];
        float p = s0 * s1;
#pragma unroll
        for (int off = 1; off < 64; off <<= 1) {
          float v = __shfl_up(p, off, 64);
          if (li >= off) p *= v;
        }
        float E = __shfl_up(p, 1, 64);
        if (li == 0) E = 1.f;
        sm[P2_SCAN + i0] = E * s0;
        sm[P2_SCAN + i1] = E * s0 * s1;
        float ex0 = (r0 > 0) ? sm[P2_SCAN + r0 - 1] : 1.f;
        float ex1 = (r1 > 0) ? sm[P2_SCAN + r1 - 1] : 1.f;
        float a0 = (1.f - u0) * ex0;
        float a1 = (1.f - u1) * ex1;
        float* ALn = sm + P2_ALLOC + ((t + 1) & 1) * 128;
        ALn[i0] = a0;
        ALn[i1] = a1;
        float as = a0 + a1;
#pragma unroll
        for (int off = 32; off > 0; off >>= 1) as += __shfl_xor(as, off, 64);
        if (li == 0) sm[P2_SCAL + ((t + 1) & 1)] = as;
      } else if (tid < 448) {        // prec update (reads OLD-parity alloc/S)
        const int n = tid - 320;     // 0..127
        float wgag = sigf(sm[P2_ITF + 128]) * sigf(sm[P2_ITF + 129]);
        float wws = wgag * sm[P2_SCAL + (t & 1)];
        sm[P2_PREC + n] = (1.f - wws) * sm[P2_PREC + n]
                        + wgag * sm[P2_ALLOC + (t & 1) * 128 + n];
      }
      __syncthreads();
      // ---- phase 6: out projection (off-chain; no trailing barrier)
      {
        const int o = tid >> 3, seg = tid & 7;
        const float4* wrow = (const float4*)(W_out + (size_t)o * 576) + seg * 18;
        const float4* hb = (const float4*)(sm + P2_H) + seg * 18;
        float p = 0.f;
#pragma unroll
        for (int q = 0; q < 18; ++q) {
          float4 w = wrow[q]; float4 h = hb[q];
          p += w.x * h.x + w.y * h.y + w.z * h.z + w.w * h.w;
        }
        p += __shfl_down(p, 4, 8);
        p += __shfl_down(p, 2, 8);
        p += __shfl_down(p, 1, 8);
        if (seg == 0) out[((size_t)b * Tt + t) * Oo + o] = p + b_out[o];
      }
    }
  }
}

extern "C" void kernel_launch(void* const* d_in, const int* in_sizes, int n_in,
                              void* d_out, int out_size, void* d_ws, size_t ws_size,
                              hipStream_t stream) {
  (void)in_sizes; (void)n_in; (void)d_ws; (void)ws_size; (void)out_size;
  const float* x    = (const float*)d_in[0];
  const float* W_ih = (const float*)d_in[1];
  const float* W_hh = (const float*)d_in[2];
  const float* b_ih = (const float*)d_in[3];
  const float* b_hh = (const float*)d_in[4];
  const float* W_if = (const float*)d_in[5];
  const float* b_if = (const float*)d_in[6];
  const float* W_out = (const float*)d_in[7];
  const float* b_out = (const float*)d_in[8];
  float* out = (float*)d_out;

  dnc_init<<<320, TIN, 0, stream>>>(W_ih, W_hh, b_ih, b_hh);

  hipFuncSetAttribute((const void*)dnc_main,
                      hipFuncAttributeMaxDynamicSharedMemorySize, SMEM_BYTES);

  void* args[] = {(void*)&x, (void*)&W_if, (void*)&b_if,
                  (void*)&W_out, (void*)&b_out, (void*)&out};
  hipLaunchCooperativeKernel((void*)dnc_main, dim3(NWG), dim3(NT), args,
                             SMEM_BYTES, stream);
}

// Round 6
// 865.974 us; speedup vs baseline: 2.4122x; 1.0885x over previous
//
#include <hip/hip_runtime.h>
#include <math.h>

// DNC: B=32,T=64,I=64,O=64,H=512,N=128,W=64,IF=198
// R19 = R14 EXACT (proven 804us; R17/R18 phase edits discarded) + ONE change:
// all multi-slot tagged waits are combined concurrent polls. Previously each
// fixwait after the first re-loaded sequentially (stale pre-loads), paying
// k x MALL-RTT per handoff; now one loop reloads all invalid slots
// back-to-back so the loads overlap -> arrival + ~1 RTT.
#define Bb 32
#define Tt 64
#define Ii 64
#define Oo 64
#define Hh 512
#define Nn 128
#define Wd 64
#define IFs 198
#define KV 640
#define G4 2048

#define NP1 128          /* 16 bb-groups x 8 jb-slices */
#define NWG 160          /* + 32 P2 wgs */
#define NT 512

// ---- LDS layout (float offsets). P1/P2 blocks overlap (roles fixed per wg).
// P2 block:
#define P2_MEM    0        /* 128*65 = 8320 */
#define P2_H      8320     /* 576 [h|rvec] */
#define P2_SCR    8896     /* 2048 */
#define P2_ITF    10944    /* 224 */
#define P2_ERASE  11168
#define P2_WVEC   11232
#define P2_USAGE  11296
#define P2_PREC   11424
#define P2_RW     11552
#define P2_WW     11680
#define P2_SCAN   11808
#define P2_SS     11936
#define P2_SCAL   12064    /* 16 */
#define P2_BIF    12080    /* 224 */
#define P2_ALLOC  12304    /* 128 (precomputed allocation weights) */
// P1 block (W_if rows padded to 68):
#define P1_WIF    0        /* 198*68 = 13464 */
#define P1_BS     13464    /* 256 */
#define P1_V      13720    /* 640 rows x 2 batches interleaved = 1280 */
#define P1_CC     15016    /* 128 */
#define P1_HSL    15144    /* 128 */
#define P1_PACC   15272    /* 32*65 float4 = 8320 */
#define SMEM_FLOATS 23592  /* 94368 B */
#define SMEM_BYTES (SMEM_FLOATS * 4)

#define S_WWSUM 0

// WT row permutation: rows = [h(512) | x(64) | rvec(64)].
__device__ __align__(16) float g_WT[KV * G4];
__device__ __align__(16) float g_bsum[G4];
typedef unsigned long long u64;
// Tagged handoffs: u64 = (step_tag << 32) | float_bits. Relaxed agent atomics.
__device__ u64 g_h64[2 * Bb * Hh];   // h, step-parity double buffer, tag t+1
__device__ u64 g_rv64[Bb * Wd];      // rvec(t) tag t+1
__device__ u64 g_if64[Bb * 8 * 200]; // itf partials [b][jb(8)][o pad200] tag t+1

__device__ __forceinline__ float sigf(float v) { return 1.f / (1.f + expf(-v)); }

__device__ __forceinline__ u64 ldrelax(const u64* p) {
  return __hip_atomic_load(p, __ATOMIC_RELAXED, __HIP_MEMORY_SCOPE_AGENT);
}
__device__ __forceinline__ void tstore(u64* p, unsigned tag, float v) {
  u64 val = ((u64)tag << 32) | (u64)__float_as_uint(v);
  __hip_atomic_store(p, val, __ATOMIC_RELAXED, __HIP_MEMORY_SCOPE_AGENT);
}
__device__ __forceinline__ float tval(u64 v) {
  return __uint_as_float((unsigned)(v & 0xffffffffu));
}
// Combined concurrent polls: reload ALL invalid slots per iteration so the
// independent loads overlap in flight (one RTT, not k serialized RTTs).
__device__ __forceinline__ void waitpair(const u64* p0, const u64* p1,
                                         u64& v0, u64& v1, unsigned tag) {
  while (((unsigned)(v0 >> 32)) != tag || ((unsigned)(v1 >> 32)) != tag) {
    __builtin_amdgcn_s_sleep(1);
    v0 = ldrelax(p0);
    v1 = ldrelax(p1);
  }
}
__device__ __forceinline__ void waitquad(const u64* p0, const u64* p1,
                                         const u64* p2, const u64* p3,
                                         u64& v0, u64& v1, u64& v2, u64& v3,
                                         unsigned tag) {
  while (((unsigned)(v0 >> 32)) != tag || ((unsigned)(v1 >> 32)) != tag ||
         ((unsigned)(v2 >> 32)) != tag || ((unsigned)(v3 >> 32)) != tag) {
    __builtin_amdgcn_s_sleep(1);
    v0 = ldrelax(p0);
    v1 = ldrelax(p1);
    v2 = ldrelax(p2);
    v3 = ldrelax(p3);
  }
}

#define TIN 512
__global__ __launch_bounds__(TIN) void dnc_init(const float* __restrict__ W_ih,
                                                const float* __restrict__ W_hh,
                                                const float* __restrict__ b_ih,
                                                const float* __restrict__ b_hh) {
  __shared__ float tile[64][65];
  const int tid = threadIdx.x;
  int i0 = blockIdx.x * blockDim.x + tid;
  int st = gridDim.x * blockDim.x;
  for (int idx = i0; idx < G4; idx += st) g_bsum[idx] = b_ih[idx] + b_hh[idx];
  for (int idx = i0; idx < 2 * Bb * Hh; idx += st) g_h64[idx] = 0ull;
  for (int idx = i0; idx < Bb * Wd; idx += st) g_rv64[idx] = 0ull;
  for (int idx = i0; idx < Bb * 8 * 200; idx += st) g_if64[idx] = 0ull;

  for (int tileId = blockIdx.x; tileId < 320; tileId += gridDim.x) {
    int tc = tileId >> 5, tj = tileId & 31;
    for (int k = tid; k < 64 * 64; k += TIN) {
      int r = k >> 6, cl = k & 63;
      int j = tj * 64 + r, c = tc * 64 + cl;
      tile[r][cl] = (c < 128) ? W_ih[j * 128 + c] : W_hh[j * 512 + (c - 128)];
    }
    __syncthreads();
    for (int k = tid; k < 64 * 64; k += TIN) {
      int cl = k >> 6, rjj = k & 63;
      int c = tc * 64 + cl;
      // rows: h u -> u ; x c -> 512+c ; rvec -> 576+(c-64)  (== 512+c)
      int rp = (c < 128) ? (512 + c) : (c - 128);
      g_WT[(size_t)rp * G4 + tj * 64 + rjj] = tile[rjj][cl];
    }
    __syncthreads();
  }
}

__global__ __launch_bounds__(NT) void dnc_main(const float* __restrict__ x,
                                               const float* __restrict__ W_if,
                                               const float* __restrict__ b_if,
                                               const float* __restrict__ W_out,
                                               const float* __restrict__ b_out,
                                               float* __restrict__ out) {
  extern __shared__ float sm[];
  const int tid = threadIdx.x;
  const int wg = blockIdx.x;

  if (wg < NP1) {
    // ======================= P1: gates GEMV + fused LSTM + itf partials
    const int jb = wg & 7;
    const int bb = wg >> 3;
    const int b0 = bb * 2;
    for (int i = tid; i < IFs * 64; i += NT) {
      int o = i >> 6, c = i & 63;
      sm[P1_WIF + o * 68 + c] = W_if[(size_t)o * Hh + jb * 64 + c];
    }
    if (tid < 64) {
      int gq = tid >> 4, m = tid & 15;
      ((float4*)(sm + P1_BS))[tid] = ((const float4*)g_bsum)[gq * 128 + jb * 16 + m];
    }
    if (tid < 128) sm[P1_CC + tid] = 0.f;
    __syncthreads();

    for (int t = 0; t < Tt; ++t) {
      {  // stage h(t-1) + x, batch-interleaved [row][bl] — CONCURRENT wait
        const u64* hsrc = g_h64 + (size_t)((t + 1) & 1) * (Bb * Hh);
        const int u = tid;
        const u64* a0 = hsrc + (size_t)b0 * Hh + u;
        const u64* a1 = hsrc + (size_t)(b0 + 1) * Hh + u;
        u64 v0 = ldrelax(a0), v1 = ldrelax(a1);
        waitpair(a0, a1, v0, v1, (unsigned)t);
        float2 hh;
        hh.x = tval(v0);
        hh.y = tval(v1);
        *(float2*)(sm + P1_V + u * 2) = hh;
        if (tid < 128) {
          const int bl2 = tid >> 6, i = tid & 63;
          float xv = x[((size_t)(b0 + bl2) * Tt + t) * Ii + i];
          sm[P1_V + (512 + i) * 2 + bl2] = xv;
        }
      }
      __syncthreads();

      {  // GEMV: 640 rows split 16 ways; each weight loaded once.
        const int fg = tid & 31, ks = tid >> 5;  // ks 0..15, rows ks*40..+39
        const int fcolA = ((fg >> 4) * 128) + jb * 16 + (fg & 15);  // gates 0,1
        const float* v2 = sm + P1_V + ks * 80;
        const float4* wpA = (const float4*)g_WT + (size_t)(ks * 40) * 512 + fcolA;
        if (ks >= 14) {  // wave 7 owns rvec rows 576..639 — CONCURRENT wait
          const int j = tid & 63;
          const u64* r0 = g_rv64 + (size_t)b0 * Wd + j;
          const u64* r1 = g_rv64 + (size_t)(b0 + 1) * Wd + j;
          u64 u0 = ldrelax(r0), u1 = ldrelax(r1);
          waitpair(r0, r1, u0, u1, (unsigned)t);
          float2 rv;
          rv.x = tval(u0);
          rv.y = tval(u1);
          *(float2*)(sm + P1_V + (576 + j) * 2) = rv;  // same-wave write->read
        }
        float4 aA0 = {0.f, 0.f, 0.f, 0.f}, aA1 = {0.f, 0.f, 0.f, 0.f};
        float4 aB0 = {0.f, 0.f, 0.f, 0.f}, aB1 = {0.f, 0.f, 0.f, 0.f};
#pragma unroll 4
        for (int r = 0; r < 40; ++r) {
          float4 wA = wpA[(size_t)r * 512];
          float4 wB = wpA[(size_t)r * 512 + 256];      // gates 2,3
          float2 vv = *(const float2*)(v2 + r * 2);
          aA0.x += wA.x * vv.x; aA0.y += wA.y * vv.x; aA0.z += wA.z * vv.x; aA0.w += wA.w * vv.x;
          aA1.x += wA.x * vv.y; aA1.y += wA.y * vv.y; aA1.z += wA.z * vv.y; aA1.w += wA.w * vv.y;
          aB0.x += wB.x * vv.x; aB0.y += wB.y * vv.x; aB0.z += wB.z * vv.x; aB0.w += wB.w * vv.x;
          aB1.x += wB.x * vv.y; aB1.y += wB.y * vv.y; aB1.z += wB.z * vv.y; aB1.w += wB.w * vv.y;
        }
        float4* pacc = (float4*)(sm + P1_PACC);
        pacc[(ks * 2 + 0) * 65 + fg] = aA0;
        pacc[(ks * 2 + 1) * 65 + fg] = aA1;
        pacc[(ks * 2 + 0) * 65 + fg + 32] = aB0;
        pacc[(ks * 2 + 1) * 65 + fg + 32] = aB1;
      }
      __syncthreads();
      if (tid < 128) {  // fused K-reduce (16 partials) + LSTM; h published tagged
        const int bl = tid >> 6, l = tid & 63;
        const float* pb = sm + P1_PACC + bl * 260 + l;
        float gv0 = 0.f, gv1 = 0.f, gv2 = 0.f, gv3 = 0.f;
#pragma unroll
        for (int ks = 0; ks < 16; ++ks) {
          const float* pk = pb + ks * 520;
          gv0 += pk[0];
          gv1 += pk[64];
          gv2 += pk[128];
          gv3 += pk[192];
        }
        float ig = gv0 + sm[P1_BS + l];
        float fg = gv1 + sm[P1_BS + 64 + l];
        float gg = gv2 + sm[P1_BS + 128 + l];
        float og = gv3 + sm[P1_BS + 192 + l];
        float co = sm[P1_CC + bl * 64 + l];
        float cn = sigf(fg) * co + sigf(ig) * tanhf(gg);
        float hn = sigf(og) * tanhf(cn);
        sm[P1_CC + bl * 64 + l] = cn;
        sm[P1_HSL + bl * 64 + l] = hn;
        tstore(g_h64 + (size_t)(t & 1) * (Bb * Hh) + (size_t)(b0 + bl) * Hh + jb * 64 + l,
               (unsigned)(t + 1), hn);
      }
      __syncthreads();
      if (tid < 2 * IFs) {  // itf partials from padded LDS W_if -> tagged stores
        const int o = tid >> 1, bl = tid & 1;
        const float4* wr = (const float4*)(sm + P1_WIF + o * 68);
        const float4* h4 = (const float4*)(sm + P1_HSL + bl * 64);
        float acc = 0.f;
#pragma unroll 8
        for (int c4 = 0; c4 < 16; ++c4) {
          float4 w = wr[c4]; float4 h = h4[c4];
          acc += w.x * h.x + w.y * h.y + w.z * h.z + w.w * h.w;
        }
        tstore(g_if64 + ((size_t)(b0 + bl) * 8 + jb) * 200 + o, (unsigned)(t + 1), acc);
      }
    }
  } else {
    // ======================= P2: DNC memory for batch b — 6-barrier structure
    const int b = wg - NP1;
    float* SCR = sm + P2_SCR;
    float regL[32], regLT[32];
#pragma unroll
    for (int k = 0; k < 32; ++k) { regL[k] = 0.f; regLT[k] = 0.f; }
    for (int i = tid; i < Nn * 65; i += NT) sm[P2_MEM + i] = 0.f;
    if (tid < 128) { sm[P2_USAGE + tid] = 0.f; sm[P2_PREC + tid] = 0.f; sm[P2_RW + tid] = 0.f; }
    if (tid < IFs) sm[P2_BIF + tid] = b_if[tid];
    __syncthreads();
    // prologue: alloc for t=0 from usage=0
    if (tid < 64) {
      const int li = tid, i0 = 2 * li, i1 = i0 + 1;
      float u0 = sm[P2_USAGE + i0], u1 = sm[P2_USAGE + i1];
      int r0 = 0, r1 = 0;
      for (int jc = 0; jc < 32; ++jc) {
        float4 uj4 = *(const float4*)(sm + P2_USAGE + jc * 4);
#pragma unroll
        for (int e = 0; e < 4; ++e) {
          float uj = (&uj4.x)[e];
          int j = jc * 4 + e;
          r0 += (uj < u0 || (uj == u0 && j < i0)) ? 1 : 0;
          r1 += (uj < u1 || (uj == u1 && j < i1)) ? 1 : 0;
        }
      }
      sm[P2_SS + r0] = u0;
      sm[P2_SS + r1] = u1;
      float s0 = sm[P2_SS + i0], s1 = sm[P2_SS + i1];
      float p = s0 * s1;
#pragma unroll
      for (int off = 1; off < 64; off <<= 1) {
        float v = __shfl_up(p, off, 64);
        if (li >= off) p *= v;
      }
      float E = __shfl_up(p, 1, 64);
      if (li == 0) E = 1.f;
      sm[P2_SCAN + i0] = E * s0;
      sm[P2_SCAN + i1] = E * s0 * s1;
      float ex0 = (r0 > 0) ? sm[P2_SCAN + r0 - 1] : 1.f;
      float ex1 = (r1 > 0) ? sm[P2_SCAN + r1 - 1] : 1.f;
      sm[P2_ALLOC + i0] = (1.f - u0) * ex0;
      sm[P2_ALLOC + i1] = (1.f - u1) * ex1;
    }
    __syncthreads();

    for (int t = 0; t < Tt; ++t) {
      // ---- phase 1: tagged itf gather — CONCURRENT quad wait
      if (tid < 2 * IFs) {
        const int o = tid >> 1, hf = tid & 1;
        const u64* src = g_if64 + ((size_t)b * 8 + hf * 4) * 200 + o;
        u64 a0 = ldrelax(src), a1 = ldrelax(src + 200),
            a2 = ldrelax(src + 400), a3 = ldrelax(src + 600);
        waitquad(src, src + 200, src + 400, src + 600, a0, a1, a2, a3,
                 (unsigned)(t + 1));
        float s = tval(a0) + tval(a1) + tval(a2) + tval(a3);
        s += __shfl_xor(s, 1, 64);
        if (hf == 0) sm[P2_ITF + o] = s + sm[P2_BIF + o];
      }
      __syncthreads();
      // ---- phase 2: wave0 short block (scalars + ww from ALLOC + usage + wwsum)
      float kn_r = 0.f, rstr_r = 0.f, rm0_r = 0.f, rm1_r = 0.f, rm2_r = 0.f;
      if (tid < 64) {
        const int li = tid, i0 = 2 * li, i1 = i0 + 1;
        float wgag = sigf(sm[P2_ITF + 128]) * sigf(sm[P2_ITF + 129]);
        float rs = sm[P2_ITF + 194];
        rstr_r = (rs > 20.f) ? rs : log1pf(expf(rs));
        float m0 = sm[P2_ITF + 195], m1 = sm[P2_ITF + 196], m2 = sm[P2_ITF + 197];
        float mx = fmaxf(m0, fmaxf(m1, m2));
        float e0 = expf(m0 - mx), e1 = expf(m1 - mx), e2 = expf(m2 - mx);
        float es = e0 + e1 + e2;
        rm0_r = e0 / es; rm1_r = e1 / es; rm2_r = e2 / es;
        float rk = sm[P2_ITF + li];
        sm[P2_ERASE + li] = sigf(rk);
        sm[P2_WVEC + li] = sm[P2_ITF + 64 + li];
        float sq = rk * rk;
#pragma unroll
        for (int off = 32; off > 0; off >>= 1) sq += __shfl_xor(sq, off, 64);
        kn_r = sqrtf(sq) + 1e-8f;
        float u0 = sm[P2_USAGE + i0], u1 = sm[P2_USAGE + i1];
        float w0 = wgag * sm[P2_ALLOC + i0];
        float w1 = wgag * sm[P2_ALLOC + i1];
        sm[P2_WW + i0] = w0; sm[P2_WW + i1] = w1;
        sm[P2_USAGE + i0] = u0 + (1.f - u0) * w0;
        sm[P2_USAGE + i1] = u1 + (1.f - u1) * w1;
        float wws = w0 + w1;
#pragma unroll
        for (int off = 32; off > 0; off >>= 1) wws += __shfl_xor(wws, off, 64);
        if (li == 0) sm[P2_SCAL + S_WWSUM] = wws;
      }
      __syncthreads();
      // ---- phase 3: pass1 (fused mem+dot+mn + register link + bw/fw partials)
      {
        const int n = tid & 127, ws = tid >> 7;
        float4 er[4], wv[4], kf[4];
#pragma unroll
        for (int r = 0; r < 4; ++r) {
          er[r] = *(const float4*)(sm + P2_ERASE + ws * 16 + r * 4);
          wv[r] = *(const float4*)(sm + P2_WVEC + ws * 16 + r * 4);
          kf[r] = *(const float4*)(sm + P2_ITF + ws * 16 + r * 4);
        }
        float wwn = sm[P2_WW + n];
        float dotp = 0.f, mnp = 0.f;
        const int base = P2_MEM + n * 65 + ws * 16;
#pragma unroll
        for (int q = 0; q < 16; ++q) {
          float m = sm[base + q];
          float ee = (&er[q >> 2].x)[q & 3];
          float vv = (&wv[q >> 2].x)[q & 3];
          float kk = (&kf[q >> 2].x)[q & 3];
          m = m * (1.f - wwn * ee) + wwn * vv;
          sm[base + q] = m;
          dotp += kk * m;
          mnp += m * m;
        }
        SCR[ws * 128 + n] = dotp;
        SCR[512 + ws * 128 + n] = mnp;
        const int m = n, ns = ws;
        float wwm = wwn;
        float prn = sm[P2_PREC + m];
        float bwp = 0.f, fwp = 0.f;
#pragma unroll
        for (int kq = 0; kq < 8; ++kq) {
          float4 ww4 = *(const float4*)(sm + P2_WW + ns * 32 + kq * 4);
          float4 pr4 = *(const float4*)(sm + P2_PREC + ns * 32 + kq * 4);
          float4 rw4 = *(const float4*)(sm + P2_RW + ns * 32 + kq * 4);
#pragma unroll
          for (int e = 0; e < 4; ++e) {
            int k = kq * 4 + e;
            int nn = ns * 32 + k;
            float wwo = (&ww4.x)[e];
            float pro = (&pr4.x)[e];
            float rwo = (&rw4.x)[e];
            float L = regL[k];
            L = (1.f - wwo - wwm) * L + pro * wwm;
            if (nn == m) L = 0.f;
            regL[k] = L;
            bwp += L * rwo;
            float LT = regLT[k];
            LT = (1.f - wwm - wwo) * LT + prn * wwo;
            if (nn == m) LT = 0.f;
            regLT[k] = LT;
            fwp += LT * rwo;
          }
        }
        SCR[1024 + ns * 128 + m] = bwp;
        SCR[1536 + ns * 128 + m] = fwp;
      }
      __syncthreads();
      // ---- phase 4: softmax + combine + normalize (pass2 FUSED: read partials)
      if (tid < 64) {
        int i0 = 2 * tid, i1 = i0 + 1;
        float d0 = SCR[i0] + SCR[128 + i0] + SCR[256 + i0] + SCR[384 + i0];
        float d1 = SCR[i1] + SCR[128 + i1] + SCR[256 + i1] + SCR[384 + i1];
        float mn0 = sqrtf(SCR[512 + i0] + SCR[640 + i0] + SCR[768 + i0] + SCR[896 + i0]) + 1e-8f;
        float mn1 = sqrtf(SCR[512 + i1] + SCR[640 + i1] + SCR[768 + i1] + SCR[896 + i1]) + 1e-8f;
        float bw0 = SCR[1024 + i0] + SCR[1152 + i0] + SCR[1280 + i0] + SCR[1408 + i0];
        float bw1 = SCR[1024 + i1] + SCR[1152 + i1] + SCR[1280 + i1] + SCR[1408 + i1];
        float fw0 = SCR[1536 + i0] + SCR[1664 + i0] + SCR[1792 + i0] + SCR[1920 + i0];
        float fw1 = SCR[1536 + i1] + SCR[1664 + i1] + SCR[1792 + i1] + SCR[1920 + i1];
        float q0 = d0 / (kn_r * mn0) * rstr_r;
        float q1 = d1 / (kn_r * mn1) * rstr_r;
        float mx = fmaxf(q0, q1);
#pragma unroll
        for (int off = 32; off > 0; off >>= 1) mx = fmaxf(mx, __shfl_xor(mx, off, 64));
        float e0 = expf(q0 - mx), e1 = expf(q1 - mx);
        float es = e0 + e1;
#pragma unroll
        for (int off = 32; off > 0; off >>= 1) es += __shfl_xor(es, off, 64);
        float wv0 = rm0_r * bw0 + rm1_r * fw0 + rm2_r * (e0 / es) + 1e-8f;
        float wv1 = rm0_r * bw1 + rm1_r * fw1 + rm2_r * (e1 / es) + 1e-8f;
        float wsum = wv0 + wv1;
#pragma unroll
        for (int off = 32; off > 0; off >>= 1) wsum += __shfl_xor(wsum, off, 64);
        sm[P2_RW + i0] = wv0 / wsum;
        sm[P2_RW + i1] = wv1 / wsum;
      }
      __syncthreads();
      // ---- phase 5: rvec partials
      {
        const int w = tid & 63, ns8 = tid >> 6;
        float4 rw4[4];
#pragma unroll
        for (int r = 0; r < 4; ++r)
          rw4[r] = *(const float4*)(sm + P2_RW + ns8 * 16 + r * 4);
        float p = 0.f;
#pragma unroll
        for (int k = 0; k < 16; ++k)
          p += (&rw4[k >> 2].x)[k & 3] * sm[P2_MEM + (ns8 * 16 + k) * 65 + w];
        SCR[ns8 * 64 + w] = p;
      }
      __syncthreads();
      // ---- phase 6 (merged): rvec reduce+publish | h gather | alloc | prec
      if (tid < 64) {          // rvec reduce -> tagged store (critical-path exit)
        float r = 0.f;
#pragma unroll
        for (int s2 = 0; s2 < 8; ++s2) r += SCR[s2 * 64 + tid];
        sm[P2_H + 512 + tid] = r;
        tstore(g_rv64 + (size_t)b * Wd + tid, (unsigned)(t + 1), r);
      } else if (tid < 320) {  // tagged h gather — CONCURRENT wait
        const int idx = tid - 64;
        const u64* hsrc = g_h64 + (size_t)(t & 1) * (Bb * Hh) + (size_t)b * Hh;
        const u64* a0 = hsrc + idx * 2;
        const u64* a1 = hsrc + idx * 2 + 1;
        u64 v0 = ldrelax(a0), v1 = ldrelax(a1);
        waitpair(a0, a1, v0, v1, (unsigned)(t + 1));
        sm[P2_H + idx * 2] = tval(v0);
        sm[P2_H + idx * 2 + 1] = tval(v1);
      } else if (tid < 384) {  // next step's alloc from usage(t) (wave 5)
        const int li = tid - 320, i0 = 2 * li, i1 = i0 + 1;
        float u0 = sm[P2_USAGE + i0], u1 = sm[P2_USAGE + i1];
        int r0 = 0, r1 = 0;
        for (int jc = 0; jc < 32; ++jc) {
          float4 uj4 = *(const float4*)(sm + P2_USAGE + jc * 4);
#pragma unroll
          for (int e = 0; e < 4; ++e) {
            float uj = (&uj4.x)[e];
            int j = jc * 4 + e;
            r0 += (uj < u0 || (uj == u0 && j < i0)) ? 1 : 0;
            r1 += (uj < u1 || (uj == u1 && j < i1)) ? 1 : 0;
          }
        }
        sm[P2_SS + r0] = u0;
        sm[P2_SS + r1] = u1;
        float s0 = sm[P2_SS + i0], s1 = sm[P2_SS + i1];
        float p = s0 * s1;
#pragma unroll
        for (int off = 1; off < 64; off <<= 1) {
          float v = __shfl_up(p, off, 64);
          if (li >= off) p *= v;
        }
        float E = __shfl_up(p, 1, 64);
        if (li == 0) E = 1.f;
        sm[P2_SCAN + i0] = E * s0;
        sm[P2_SCAN + i1] = E * s0 * s1;
        float ex0 = (r0 > 0) ? sm[P2_SCAN + r0 - 1] : 1.f;
        float ex1 = (r1 > 0) ? sm[P2_SCAN + r1 - 1] : 1.f;
        sm[P2_ALLOC + i0] = (1.f - u0) * ex0;
        sm[P2_ALLOC + i1] = (1.f - u1) * ex1;
      } else {                 // prec update (hoisted from old pass2)
        const int n = tid - 384;   // 0..127
        float wws = sm[P2_SCAL + S_WWSUM];
        sm[P2_PREC + n] = (1.f - wws) * sm[P2_PREC + n] + sm[P2_WW + n];
      }
      __syncthreads();
      // ---- phase 7: out projection (no trailing barrier needed)
      {
        const int o = tid >> 3, seg = tid & 7;
        const float4* wrow = (const float4*)(W_out + (size_t)o * 576) + seg * 18;
        const float4* hb = (const float4*)(sm + P2_H) + seg * 18;
        float p = 0.f;
#pragma unroll
        for (int q = 0; q < 18; ++q) {
          float4 w = wrow[q]; float4 h = hb[q];
          p += w.x * h.x + w.y * h.y + w.z * h.z + w.w * h.w;
        }
        p += __shfl_down(p, 4, 8);
        p += __shfl_down(p, 2, 8);
        p += __shfl_down(p, 1, 8);
        if (seg == 0) out[((size_t)b * Tt + t) * Oo + o] = p + b_out[o];
      }
    }
  }
}

extern "C" void kernel_launch(void* const* d_in, const int* in_sizes, int n_in,
                              void* d_out, int out_size, void* d_ws, size_t ws_size,
                              hipStream_t stream) {
  (void)in_sizes; (void)n_in; (void)d_ws; (void)ws_size; (void)out_size;
  const float* x    = (const float*)d_in[0];
  const float* W_ih = (const float*)d_in[1];
  const float* W_hh = (const float*)d_in[2];
  const float* b_ih = (const float*)d_in[3];
  const float* b_hh = (const float*)d_in[4];
  const float* W_if = (const float*)d_in[5];
  const float* b_if = (const float*)d_in[6];
  const float* W_out = (const float*)d_in[7];
  const float* b_out = (const float*)d_in[8];
  float* out = (float*)d_out;

  dnc_init<<<320, TIN, 0, stream>>>(W_ih, W_hh, b_ih, b_hh);

  hipFuncSetAttribute((const void*)dnc_main,
                      hipFuncAttributeMaxDynamicSharedMemorySize, SMEM_BYTES);

  void* args[] = {(void*)&x, (void*)&W_if, (void*)&b_if,
                  (void*)&W_out, (void*)&b_out, (void*)&out};
  hipLaunchCooperativeKernel((void*)dnc_main, dim3(NWG), dim3(NT), args,
                             SMEM_BYTES, stream);
}